// Round 7
// baseline (417.805 us; speedup 1.0000x reference)
//
#include <hip/hip_runtime.h>
#include <math.h>

#define B_ 16
#define S_ 1024
#define D_ 512
#define H_ 4
#define INV_TEMP 0.044194173824159216f   // 1/sqrt(512)
#define C_SCALE 0.00390625f              // 2^-8: keeps head-4 scores inside fp16 range
#define OUT_SCALE 256.0f

typedef _Float16 f16;
typedef _Float16 f16x8 __attribute__((ext_vector_type(8)));
typedef _Float16 f16x4 __attribute__((ext_vector_type(4)));
typedef float f32x4 __attribute__((ext_vector_type(4)));

#define AS1(p) ((const __attribute__((address_space(1))) void*)(p))
#define AS3(p) ((__attribute__((address_space(3))) void*)(p))
#define MFMA __builtin_amdgcn_mfma_f32_16x16x32_f16

// raw barrier (no vmcnt drain) + sched fences pinning phase boundaries
#define SBAR()                                                                 \
    do {                                                                       \
        __builtin_amdgcn_sched_barrier(0);                                     \
        __builtin_amdgcn_s_barrier();                                          \
        __builtin_amdgcn_sched_barrier(0);                                     \
    } while (0)

#define VMF(N)                                                                 \
    do {                                                                       \
        __builtin_amdgcn_sched_barrier(0);                                     \
        asm volatile("s_waitcnt vmcnt(" #N ")" ::: "memory");                  \
        __builtin_amdgcn_sched_barrier(0);                                     \
    } while (0)

// ---------------------------------------------------------------------------
// fp32 -> fp16 convert
// ---------------------------------------------------------------------------
__global__ __launch_bounds__(256)
void k_conv(const float* __restrict__ src, f16* __restrict__ dst)
{
    const int i = blockIdx.x * 256 + threadIdx.x;
    const float4 v = ((const float4*)src)[i];
    f16x4 h; h[0] = (f16)v.x; h[1] = (f16)v.y; h[2] = (f16)v.z; h[3] = (f16)v.w;
    ((f16x4*)dst)[i] = h;
}

// ---------------------------------------------------------------------------
// pad flags: flag[b*8+kt] = 1 iff any event_type[b, kt*128 .. kt*128+127]==0
// ---------------------------------------------------------------------------
__global__ __launch_bounds__(128)
void k_flags(const int* __restrict__ etype, int* __restrict__ flag)
{
    const int t = threadIdx.x;           // 128 = B_ * 8
    const int b = t >> 3, kt = t & 7;
    const int* p = etype + b * S_ + kt * 128;
    int any0 = 0;
#pragma unroll
    for (int i = 0; i < 128; i += 4) {
        const int4 v = *(const int4*)(p + i);
        any0 |= (v.x == 0) | (v.y == 0) | (v.z == 0) | (v.w == 0);
    }
    flag[t] = any0;
}

// ===========================================================================
// 256x256xK512 8-phase pipeline (m201 template), BK=64, 512 thr / 8 waves
// (2M x 4N). LDS: buf0.A @0 buf0.B @32768 | buf1.A @65536 buf1.B @98304.
// T2 swizzle: LDS row slot s holds global col-group (s ^ (row&7)); applied
// as pre-swizzled global source (linear LDS dest) + swizzled ds_read.
// vmcnt ledger (per wave, 2 ops per stage_half):
//   prologue 12 ops -> VMF(4): K0.A,K0.B land; K1.B in flight.
//   each iter: +4A +4B issued, VMF(4) per K-tile -> next tile's A,B landed
//   before its phases; 4 ops (next B) stay in flight across the barrier.
//   tail: VMF(0) before buf1 phases; no stages after.
// ===========================================================================
__device__ __forceinline__ void stage_half(const f16* __restrict__ mat, int ld,
                                           int koff, int rowbase,
                                           char* lds, int dstbase, int t)
{
    // half-tile = 128 rows x 64 f16 = 16KB = 2 ops (64 rows each)
    const int r = rowbase + (t >> 3);
    const int c = ((t & 7) ^ ((t >> 3) & 7)) << 3;   // pre-swizzled col group
    const f16* g0 = mat + (size_t)r * ld + koff + c;
    __builtin_amdgcn_global_load_lds(AS1(g0), AS3(lds + dstbase + t * 16), 16, 0, 0);
    const f16* g1 = g0 + (size_t)64 * ld;            // (r+64)&7 == r&7
    __builtin_amdgcn_global_load_lds(AS1(g1), AS3(lds + dstbase + 8192 + t * 16), 16, 0, 0);
}

// One phase: quad P of the current K-tile. B (all 4 N-frags x 2 kk) read at
// P==0 only; A-rows (2P,2P+1) read every phase. One half-tile stage issued
// into an INACTIVE region. barrier -> lgkmcnt(0)+sched fence -> 16 MFMA
// (setprio-wrapped) -> optional vm fence -> barrier.
#define PHASE(P, ABASE, BBASE, FENCE, ...)                                     \
    {                                                                          \
        f16x8 ar[2][2];                                                        \
        if ((P) == 0) {                                                        \
            _Pragma("unroll") for (int nj_ = 0; nj_ < 4; ++nj_)                \
                _Pragma("unroll") for (int kk_ = 0; kk_ < 2; ++kk_)            \
                    br[nj_][kk_] =                                             \
                        *(const f16x8*)(lds + (BBASE) + offB[nj_][kk_]);       \
        }                                                                      \
        _Pragma("unroll") for (int f_ = 0; f_ < 2; ++f_)                       \
            _Pragma("unroll") for (int kk_ = 0; kk_ < 2; ++kk_)                \
                ar[f_][kk_] =                                                  \
                    *(const f16x8*)(lds + (ABASE) + offA[2 * (P) + f_][kk_]);  \
        __VA_ARGS__;                                                           \
        SBAR();                                                                \
        asm volatile("s_waitcnt lgkmcnt(0)" ::: "memory");                     \
        __builtin_amdgcn_sched_barrier(0);                                     \
        __builtin_amdgcn_s_setprio(1);                                         \
        _Pragma("unroll") for (int f_ = 0; f_ < 2; ++f_)                       \
            _Pragma("unroll") for (int nj_ = 0; nj_ < 4; ++nj_)                \
                _Pragma("unroll") for (int kk_ = 0; kk_ < 2; ++kk_)            \
                    acc[2 * (P) + f_][nj_] = MFMA(ar[f_][kk_], br[nj_][kk_],   \
                                                  acc[2 * (P) + f_][nj_],      \
                                                  0, 0, 0);                    \
        __builtin_amdgcn_s_setprio(0);                                         \
        FENCE;                                                                 \
        SBAR();                                                                \
    }

__device__ __forceinline__ void gemm256_k512(const f16* __restrict__ A, int ldA,
                                             const f16* __restrict__ Bm, int ldB,
                                             char* lds, int t, f32x4 (*acc)[4])
{
    const int lane = t & 63, lr = lane & 15, quad = lane >> 4;
    const int w = t >> 6, wm = w >> 2, wn = w & 3;

    // swizzled ds_read byte offsets: row*128 + ((g ^ (row&7)) << 4),
    // g = kk*4 + quad (global col-group for MFMA k-chunk kk).
    int offA[8][2], offB[4][2];
#pragma unroll
    for (int fi = 0; fi < 8; ++fi) {
        const int row = wm * 128 + fi * 16 + lr;
#pragma unroll
        for (int kk = 0; kk < 2; ++kk)
            offA[fi][kk] = row * 128 + ((((kk << 2) + quad) ^ (row & 7)) << 4);
    }
#pragma unroll
    for (int nj = 0; nj < 4; ++nj) {
        const int row = wn * 64 + nj * 16 + lr;
#pragma unroll
        for (int kk = 0; kk < 2; ++kk)
            offB[nj][kk] = row * 128 + ((((kk << 2) + quad) ^ (row & 7)) << 4);
    }

    f16x8 br[4][2];

    // prologue: K0 full + K1.B
    stage_half(A,  ldA, 0,  0,   lds, 0,      t);
    stage_half(A,  ldA, 0,  128, lds, 16384,  t);
    stage_half(Bm, ldB, 0,  0,   lds, 32768,  t);
    stage_half(Bm, ldB, 0,  128, lds, 49152,  t);
    stage_half(Bm, ldB, 64, 0,   lds, 98304,  t);
    stage_half(Bm, ldB, 64, 128, lds, 114688, t);
    VMF(4);      // K0 landed (per wave); K1.B in flight
    SBAR();      // cross-wave landing guarantee

#pragma unroll 1
    for (int it = 0; it < 3; ++it) {
        const int ko1 = it * 128 + 64, ko2 = it * 128 + 128, ko3 = it * 128 + 192;
        // ---- K-tile 2it in buf0 ----
        PHASE(0, 0, 32768, (void)0, stage_half(A, ldA, ko1, 0,   lds, 65536, t))
        PHASE(1, 0, 32768, (void)0, stage_half(A, ldA, ko1, 128, lds, 81920, t))
        PHASE(2, 0, 32768, (void)0, stage_half(Bm, ldB, ko2, 0,   lds, 32768, t))
        PHASE(3, 0, 32768, VMF(4),  stage_half(Bm, ldB, ko2, 128, lds, 49152, t))
        // ---- K-tile 2it+1 in buf1 ----
        PHASE(0, 65536, 98304, (void)0, stage_half(A, ldA, ko2, 0,   lds, 0,      t))
        PHASE(1, 65536, 98304, (void)0, stage_half(A, ldA, ko2, 128, lds, 16384,  t))
        PHASE(2, 65536, 98304, (void)0, stage_half(Bm, ldB, ko3, 0,   lds, 98304,  t))
        PHASE(3, 65536, 98304, VMF(4),  stage_half(Bm, ldB, ko3, 128, lds, 114688, t))
    }
    // tail: K-tile 6 (buf0) then 7 (buf1); only K7.A left to stage.
    PHASE(0, 0, 32768, (void)0, stage_half(A, ldA, 448, 0,   lds, 65536, t))
    PHASE(1, 0, 32768, (void)0, stage_half(A, ldA, 448, 128, lds, 81920, t))
    PHASE(2, 0, 32768, (void)0, (void)0)
    PHASE(3, 0, 32768, VMF(0),  (void)0)
    PHASE(0, 65536, 98304, (void)0, (void)0)
    PHASE(1, 65536, 98304, (void)0, (void)0)
    PHASE(2, 65536, 98304, (void)0, (void)0)
    PHASE(3, 65536, 98304, (void)0, (void)0)
}

// ===========================================================================
// Merged per-head producer (512 thr, 384 blocks):
//   blocks [0,256): scores 256x256 tiles (upper-tri + pad kept) + fused ss
//   blocks [256,384): vT = ELU(x @ W^T + b)^T stored [B][D][S] fp16
// ===========================================================================
__global__ __launch_bounds__(512)
void k_vs(const f16* __restrict__ xh, const f16* __restrict__ Wh,
          const float* __restrict__ bias, f16* __restrict__ vT,
          const int* __restrict__ etype, const int* __restrict__ flag,
          f16* __restrict__ sh, float* __restrict__ ss)
{
    __shared__ __align__(16) char lds[131072];
    const int t = threadIdx.x;
    const int lane = t & 63, lr = lane & 15, quad = lane >> 4;
    const int w = t >> 6, wm = w >> 2, wn = w & 3;

    if (blockIdx.x < 256) {
        // ---------------- scores ----------------
        const int i0 = blockIdx.x;
        const int xcd = i0 & 7, j0 = i0 >> 3;          // j0 in [0,32)
        const int b = 2 * xcd + (j0 & 1);
        const int tile = j0 >> 1;                      // [0,16)
        const int kt2 = tile & 3, qt2 = tile >> 2;
        // fully-masked 256-tile: exact zero (sh zeroed up front; ss contrib 0)
        if (kt2 < qt2 && !(flag[b * 8 + 2 * kt2] | flag[b * 8 + 2 * kt2 + 1]))
            return;                                    // block-uniform exit
        const int bk = kt2 * 256, bq = qt2 * 256;
        const f16* xb = xh + (size_t)b * S_ * D_;
        f32x4 acc[8][4] = {};
        gemm256_k512(xb + (size_t)bk * D_, D_, xb + (size_t)bq * D_, D_,
                     lds, t, acc);
        const float sc = INV_TEMP * C_SCALE;
        float ssq[4] = {0.f, 0.f, 0.f, 0.f};
#pragma unroll
        for (int fi = 0; fi < 8; ++fi) {
            const int k4 = bk + wm * 128 + fi * 16 + quad * 4;
            const int4 et = *(const int4*)(etype + b * S_ + k4);
            const int ev[4] = {et.x, et.y, et.z, et.w};
#pragma unroll
            for (int nj = 0; nj < 4; ++nj) {
                const int q = bq + wn * 64 + nj * 16 + lr;
                f16x4 hv;
#pragma unroll
                for (int r = 0; r < 4; ++r) {
                    const bool keep = ((k4 + r) > q) || (ev[r] == 0);
                    hv[r] = (f16)(keep ? acc[fi][nj][r] * sc : 0.0f);
                    const float fv = (float)hv[r];
                    ssq[nj] += fv * fv;          // sum of squares of STORED fp16
                }
                *(f16x4*)(sh + ((size_t)b * S_ + q) * S_ + k4) = hv;
            }
        }
        // fold the 4 quads (k-direction) -> one atomic per (q, wave); the two
        // wm-waves of the same wn add their 128-key halves via the atomic.
#pragma unroll
        for (int nj = 0; nj < 4; ++nj) {
            float v = ssq[nj];
            v += __shfl_xor(v, 16, 64);
            v += __shfl_xor(v, 32, 64);
            if (quad == 0)
                atomicAdd(ss + b * S_ + (bq + wn * 64 + nj * 16 + lr), v);
        }
    } else {
        // ---------------- vT = ELU(x @ W^T + b)^T ----------------
        const int idx = blockIdx.x - 256;
        const int xcd = idx & 7, j = idx >> 3;         // j in [0,16)
        const int b = 2 * xcd + (j & 1);
        const int rest = j >> 1;                       // [0,8)
        const int sq = rest & 3, bnT = rest >> 2;
        const int bm = b * 1024 + sq * 256;            // rows of x (batch b)
        const int bn = bnT * 256;                      // output features e
        f32x4 acc[8][4] = {};
        gemm256_k512(xh + (size_t)bm * D_, D_, Wh + (size_t)bn * D_, D_,
                     lds, t, acc);
#pragma unroll
        for (int nj = 0; nj < 4; ++nj) {
            const int e = bn + wn * 64 + nj * 16 + lr;
            const float be = bias[e];
#pragma unroll
            for (int fi = 0; fi < 8; ++fi) {
                const int m = bm + wm * 128 + fi * 16 + quad * 4;
                const int s = m & 1023;               // batch == b by construction
                f16x4 hv;
#pragma unroll
                for (int r = 0; r < 4; ++r) {
                    float z = acc[fi][nj][r] + be;
                    z = (z > 0.0f) ? z : (expf(z) - 1.0f);
                    hv[r] = (f16)z;
                }
                *(f16x4*)(vT + ((size_t)b * D_ + e) * S_ + s) = hv;
            }
        }
    }
}

// ---------------------------------------------------------------------------
// k_out primitives: EXACT round-2 proven single-buffer 2-phase core.
// ---------------------------------------------------------------------------
__device__ __forceinline__ void stage128x32(const f16* __restrict__ src, int ld,
                                            char* lds0, int t)
{
    const f16* g0 = src + (size_t)(t >> 2) * ld + (t & 3) * 8;
    __builtin_amdgcn_global_load_lds(AS1(g0), AS3(lds0 + t * 16), 16, 0, 0);
    const f16* g1 = g0 + (size_t)64 * ld;
    __builtin_amdgcn_global_load_lds(AS1(g1), AS3(lds0 + 4096 + t * 16), 16, 0, 0);
}

__device__ __forceinline__ void mma_chunk(const char* ldsA, const char* ldsB,
                                          int wm, int wn, int lr, int quad,
                                          f32x4 (*acc)[4])
{
    f16x8 af[4], bf[4];
#pragma unroll
    for (int i = 0; i < 4; ++i)
        af[i] = *(const f16x8*)(ldsA + ((wm * 64 + i * 16 + lr) * 32 + quad * 8) * 2);
#pragma unroll
    for (int j = 0; j < 4; ++j)
        bf[j] = *(const f16x8*)(ldsB + ((wn * 64 + j * 16 + lr) * 32 + quad * 8) * 2);
#pragma unroll
    for (int i = 0; i < 4; ++i)
#pragma unroll
        for (int j = 0; j < 4; ++j)
            acc[i][j] = MFMA(af[i], bf[j], acc[i][j], 0, 0, 0);
}

// ===========================================================================
// k_out: 512 blocks, XCD-pinned, 128x128 tiles, round-2 proven structure.
// Kept key-chunks compacted into a block-uniform 32-wide K-offset list.
// inv computed inline from the fused Sum(s^2). wxh=0 on the last head
// (xh becomes dead — skip the store).
// ===========================================================================
__global__ __launch_bounds__(256)
void k_out(const f16* __restrict__ vT, const f16* __restrict__ sh,
           const float* __restrict__ ss, const int* __restrict__ flag,
           f16* __restrict__ xh, float* __restrict__ out,
           const int accum, const int wxh)
{
    __shared__ __align__(16) char lds[16384];
    __shared__ int klist[32];
    __shared__ int kcnt;
    const int t = threadIdx.x;
    const int w = t >> 6, lane = t & 63, lr = lane & 15, quad = lane >> 4;
    const int wm = w & 1, wn = w >> 1;
    const int i0 = blockIdx.x;
    const int xcd = i0 & 7, j0 = i0 >> 3;          // j0 in [0,64)
    const int b = 2 * xcd + (j0 & 1);
    const int tile = j0 >> 1;                      // [0,32)
    const int be = (tile & 3) * 128;               // e (M), fastest
    const int bq = (tile >> 2) * 128;              // q (N)
    const int qt = bq >> 7;

    if (t == 0) {
        int n = 0;
        for (int kc = 0; kc < 8; ++kc)
            if (kc >= qt || flag[b * 8 + kc]) {    // kept chunk
                const int kb = kc * 128;
                klist[n] = kb; klist[n + 1] = kb + 32;
                klist[n + 2] = kb + 64; klist[n + 3] = kb + 96;
                n += 4;
            }
        kcnt = n;
    }
    __syncthreads();
    const int nst = kcnt;

    const f16* Abase = vT + ((size_t)b * D_ + be) * S_;
    const f16* Bbase = sh + ((size_t)b * S_ + bq) * S_;
    f32x4 acc[4][4] = {};
#pragma unroll 1
    for (int i = 0; i < nst; ++i) {
        const int k0 = klist[i];
        stage128x32(Abase + k0, S_, lds, t);
        stage128x32(Bbase + k0, S_, lds + 8192, t);
        __syncthreads();
        mma_chunk(lds, lds + 8192, wm, wn, lr, quad, acc);
        __syncthreads();
    }

#pragma unroll
    for (int j = 0; j < 4; ++j) {
        const int q = bq + wn * 64 + j * 16 + lr;
        const float ssv = ss[b * S_ + q];
        const float scl = 1.0f / (C_SCALE * fmaxf(sqrtf(ssv) * OUT_SCALE, 1e-5f));
#pragma unroll
        for (int i = 0; i < 4; ++i) {
            const int e4 = be + wm * 64 + i * 16 + quad * 4;
            const size_t o = ((size_t)b * S_ + q) * D_ + e4;
            f32x4 xnew;
            f16x4 hx;
#pragma unroll
            for (int r = 0; r < 4; ++r) {
                xnew[r] = acc[i][j][r] * scl;
                hx[r] = (f16)xnew[r];
            }
            f32x4 val = xnew;
            if (accum) { const f32x4 old = *(const f32x4*)(out + o); val = val + old; }
            *(f32x4*)(out + o) = val;
            if (wxh) *(f16x4*)(xh + o) = hx;
        }
    }
}

// ---------------------------------------------------------------------------
// Workspace: xh @0 (16M), vT @16M (16M), sh @32M (32M), Wh @64M (2M),
//            ss  @66M (4 heads x 64K = 256K), flags @66M+256K (512B)
// ---------------------------------------------------------------------------
extern "C" void kernel_launch(void* const* d_in, const int* in_sizes, int n_in,
                              void* d_out, int out_size, void* d_ws, size_t ws_size,
                              hipStream_t stream) {
    const float* x0    = (const float*)d_in[0];
    const int*   etype = (const int*)d_in[2];
    const float* W     = (const float*)d_in[3];
    const float* bias  = (const float*)d_in[4];
    float* out = (float*)d_out;

    char* ws = (char*)d_ws;
    f16*   xh    = (f16*)(ws);
    f16*   vT    = (f16*)(ws + (16u << 20));
    f16*   sh    = (f16*)(ws + (32u << 20));
    f16*   Wh    = (f16*)(ws + (64u << 20));
    float* ssb   = (float*)(ws + (66u << 20));
    int*   flags = (int*)(ws + (66u << 20) + 262144);

    k_conv <<<8192, 256, 0, stream>>>(x0, xh);
    k_conv <<<1024, 256, 0, stream>>>(W, Wh);
    k_flags<<<1, 128, 0, stream>>>(etype, flags);
    // zero sh once: skipped (never-written) tiles must read as exact zeros;
    // the skip set is head-invariant so one memset covers all 4 heads.
    hipMemsetAsync(sh, 0, (size_t)32 << 20, stream);
    // zero all 4 per-head Sum(s^2) accumulators once.
    hipMemsetAsync(ssb, 0, 4 * (size_t)B_ * S_ * sizeof(float), stream);

    for (int h = 0; h < H_; ++h) {
        float* ss = ssb + (size_t)h * B_ * S_;
        k_vs <<<384, 512, 0, stream>>>(xh, Wh + (size_t)h * D_ * D_,
                                       bias + (size_t)h * D_, vT,
                                       etype, flags, sh, ss);
        k_out<<<512, 256, 0, stream>>>(vT, sh, ss, flags, xh, out,
                                       h > 0, h < H_ - 1);
    }
}

// Round 8
// 363.426 us; speedup vs baseline: 1.1496x; 1.1496x over previous
//
#include <hip/hip_runtime.h>
#include <math.h>

#define B_ 16
#define S_ 1024
#define D_ 512
#define H_ 4
#define INV_TEMP 0.044194173824159216f   // 1/sqrt(512)
#define C_SCALE 0.00390625f              // 2^-8: keeps head-4 scores inside fp16 range
#define OUT_SCALE 256.0f

typedef _Float16 f16;
typedef _Float16 f16x8 __attribute__((ext_vector_type(8)));
typedef _Float16 f16x4 __attribute__((ext_vector_type(4)));
typedef float f32x4 __attribute__((ext_vector_type(4)));

#define AS1(p) ((const __attribute__((address_space(1))) void*)(p))
#define AS3(p) ((__attribute__((address_space(3))) void*)(p))
#define MFMA __builtin_amdgcn_mfma_f32_16x16x32_f16

// ---------------------------------------------------------------------------
// fp32 -> fp16 convert
// ---------------------------------------------------------------------------
__global__ __launch_bounds__(256)
void k_conv(const float* __restrict__ src, f16* __restrict__ dst)
{
    const int i = blockIdx.x * 256 + threadIdx.x;
    const float4 v = ((const float4*)src)[i];
    f16x4 h; h[0] = (f16)v.x; h[1] = (f16)v.y; h[2] = (f16)v.z; h[3] = (f16)v.w;
    ((f16x4*)dst)[i] = h;
}

// ---------------------------------------------------------------------------
// pad flags: flag[b*8+kt] = 1 iff any event_type[b, kt*128 .. kt*128+127]==0
// ---------------------------------------------------------------------------
__global__ __launch_bounds__(128)
void k_flags(const int* __restrict__ etype, int* __restrict__ flag)
{
    const int t = threadIdx.x;           // 128 = B_ * 8
    const int b = t >> 3, kt = t & 7;
    const int* p = etype + b * S_ + kt * 128;
    int any0 = 0;
#pragma unroll
    for (int i = 0; i < 128; i += 4) {
        const int4 v = *(const int4*)(p + i);
        any0 |= (v.x == 0) | (v.y == 0) | (v.z == 0) | (v.w == 0);
    }
    flag[t] = any0;
}

// ---------------------------------------------------------------------------
// m97-style staging/MMA core (proven round 2 — single buffer, 2 barriers per
// K-step). Schedule-lane verdict after rounds 3-7: explicit dbuf (dynamic or
// static) and 8-phase counted-vmcnt both regress or wedge at this scale —
// hipcc inserts its own vmcnt(0) around global_load_lds-aliasing LDS reads.
// Do not touch the sync structure.
// ---------------------------------------------------------------------------
__device__ __forceinline__ void stage128x32(const f16* __restrict__ src, int ld,
                                            char* lds0, int t)
{
    const f16* g0 = src + (size_t)(t >> 2) * ld + (t & 3) * 8;
    __builtin_amdgcn_global_load_lds(AS1(g0), AS3(lds0 + t * 16), 16, 0, 0);
    const f16* g1 = g0 + (size_t)64 * ld;
    __builtin_amdgcn_global_load_lds(AS1(g1), AS3(lds0 + 4096 + t * 16), 16, 0, 0);
}

__device__ __forceinline__ void mma_chunk(const char* ldsA, const char* ldsB,
                                          int wm, int wn, int lr, int quad,
                                          f32x4 (*acc)[4])
{
    f16x8 af[4], bf[4];
#pragma unroll
    for (int i = 0; i < 4; ++i)
        af[i] = *(const f16x8*)(ldsA + ((wm * 64 + i * 16 + lr) * 32 + quad * 8) * 2);
#pragma unroll
    for (int j = 0; j < 4; ++j)
        bf[j] = *(const f16x8*)(ldsB + ((wn * 64 + j * 16 + lr) * 32 + quad * 8) * 2);
#pragma unroll
    for (int i = 0; i < 4; ++i)
#pragma unroll
        for (int j = 0; j < 4; ++j)
            acc[i][j] = MFMA(af[i], bf[j], acc[i][j], 0, 0, 0);
}

__device__ __forceinline__ void gemm_core(const f16* A, int ldA, const f16* Bm, int ldB,
                                          int K, char* lds, int t, int wm, int wn,
                                          int lr, int quad, f32x4 (*acc)[4])
{
    for (int k0 = 0; k0 < K; k0 += 32) {
        stage128x32(A + k0, ldA, lds, t);
        stage128x32(Bm + k0, ldB, lds + 8192, t);
        __syncthreads();
        mma_chunk(lds, lds + 8192, wm, wn, lr, quad, acc);
        __syncthreads();
    }
}

// ===========================================================================
// Merged per-head producer kernel (exact round-2 version, 371.6 us proven):
//   blocks [0,1024): scores (~44% early-exit) + fused Sum(s^2) via atomics
//   blocks [1024,1536): vT = ELU(x @ W^T + b)^T stored [B][D][S] fp16
// ===========================================================================
__global__ __launch_bounds__(256)
void k_vs(const f16* __restrict__ xh, const f16* __restrict__ Wh,
          const float* __restrict__ bias, f16* __restrict__ vT,
          const int* __restrict__ etype, const int* __restrict__ flag,
          f16* __restrict__ sh, float* __restrict__ ss)
{
    __shared__ __align__(16) char lds[16384];
    const int t = threadIdx.x;
    const int w = t >> 6, lane = t & 63, lr = lane & 15, quad = lane >> 4;
    const int wm = w & 1, wn = w >> 1;

    if (blockIdx.x < 1024) {
        // ---------------- scores ----------------
        const int i0 = blockIdx.x;
        const int xcd = i0 & 7, j0 = i0 >> 3;          // j0 in [0,128)
        const int b = 2 * xcd + (j0 & 1);
        const int tile = j0 >> 1;                      // [0,64)
        const int bk = (tile & 7) * 128;               // keys (M)
        const int bq = (tile >> 3) * 128;              // queries (N)
        // fully-masked tile: exact zero; never computed, never written
        // (sh zeroed once up front; ss contribution is exactly 0).
        if (bk < bq && !flag[b * 8 + (bk >> 7)]) return;

        const f16* xb = xh + (size_t)b * S_ * D_;
        f32x4 acc[4][4] = {};
        gemm_core(xb + (size_t)bk * D_, D_, xb + (size_t)bq * D_, D_, D_,
                  lds, t, wm, wn, lr, quad, acc);
        const float sc = INV_TEMP * C_SCALE;
        float ssq[4] = {0.0f, 0.0f, 0.0f, 0.0f};
#pragma unroll
        for (int i = 0; i < 4; ++i) {
            const int k4 = bk + wm * 64 + i * 16 + quad * 4;
            const int4 et = *(const int4*)(etype + b * S_ + k4);
            const int ev[4] = {et.x, et.y, et.z, et.w};
#pragma unroll
            for (int j = 0; j < 4; ++j) {
                const int q = bq + wn * 64 + j * 16 + lr;
                f16x4 hv;
#pragma unroll
                for (int r = 0; r < 4; ++r) {
                    const bool keep = ((k4 + r) > q) || (ev[r] == 0);
                    hv[r] = (f16)(keep ? acc[i][j][r] * sc : 0.0f);
                    const float fv = (float)hv[r];
                    ssq[j] += fv * fv;               // sum of squares of STORED fp16
                }
                *(f16x4*)(sh + ((size_t)b * S_ + q) * S_ + k4) = hv;
            }
        }
#pragma unroll
        for (int j = 0; j < 4; ++j) {
            float v = ssq[j];
            v += __shfl_xor(v, 16, 64);
            v += __shfl_xor(v, 32, 64);
            if (quad == 0) {
                const int q = bq + wn * 64 + j * 16 + lr;
                atomicAdd(ss + b * S_ + q, v);
            }
        }
    } else {
        // ---------------- vT = ELU(x @ W^T + b)^T ----------------
        const int idx = blockIdx.x - 1024;
        const int bm = (idx & 127) * 128;              // rows of x (B*S)
        const int bn = (idx >> 7) * 128;               // output features e
        f32x4 acc[4][4] = {};
        gemm_core(xh + (size_t)bm * D_, D_, Wh + (size_t)bn * D_, D_, D_,
                  lds, t, wm, wn, lr, quad, acc);
#pragma unroll
        for (int j = 0; j < 4; ++j) {
            const int e = bn + wn * 64 + j * 16 + lr;
            const float be = bias[e];
#pragma unroll
            for (int i = 0; i < 4; ++i) {
                const int m = bm + wm * 64 + i * 16 + quad * 4;
                const int batch = m >> 10, s = m & 1023;
                f16x4 hv;
#pragma unroll
                for (int r = 0; r < 4; ++r) {
                    float z = acc[i][j][r] + be;
                    z = (z > 0.0f) ? z : (expf(z) - 1.0f);
                    hv[r] = (f16)z;
                }
                *(f16x4*)(vT + ((size_t)batch * D_ + e) * S_ + s) = hv;
            }
        }
    }
}

// ===========================================================================
// k_out: 512 blocks x 512 thr (8 waves). Same 128x128 tile and proven
// 2-phase core, but the kept-K list is split between TWO 4-wave groups,
// each with its own 16KB LDS buffer pair, sharing block-wide barriers.
// Rationale: k_out ran ~230 TF vs k_vs 450 on the identical core — the
// barrier drain was exposed at 8 waves/CU. Two groups double MFMA and
// staged bytes per barrier period and halve the number of periods.
// Deterministic combine: group1 -> LDS -> group0 adds (fixed order).
// ===========================================================================
__global__ __launch_bounds__(512)
void k_out(const f16* __restrict__ vT, const f16* __restrict__ sh,
           const float* __restrict__ ss, const int* __restrict__ flag,
           f16* __restrict__ xh, float* __restrict__ out,
           const int accum, const int wxh)
{
    __shared__ __align__(16) char lds[65536];   // staging g0 @0, g1 @16384; combine reuses [0,64K)
    __shared__ int klist[32];
    __shared__ int kcnt;
    const int t = threadIdx.x;
    const int g = t >> 8;                       // K-half group
    const int tl = t & 255;                     // thread id within group
    const int w = tl >> 6, lane = tl & 63, lr = lane & 15, quad = lane >> 4;
    const int wm = w & 1, wn = w >> 1;
    const int i0 = blockIdx.x;
    const int xcd = i0 & 7, j0 = i0 >> 3;       // j0 in [0,64)
    const int b = 2 * xcd + (j0 & 1);
    const int tile = j0 >> 1;                   // [0,32)
    const int be = (tile & 3) * 128;            // e (M), fastest
    const int bq = (tile >> 2) * 128;           // q (N)
    const int qt = bq >> 7;

    if (t == 0) {
        int n = 0;
        for (int kc = 0; kc < 8; ++kc)
            if (kc >= qt || flag[b * 8 + kc]) { // kept chunk
                const int kb = kc * 128;
                klist[n] = kb; klist[n + 1] = kb + 32;
                klist[n + 2] = kb + 64; klist[n + 3] = kb + 96;
                n += 4;
            }
        kcnt = n;                               // multiple of 4, >= 4
    }
    __syncthreads();
    const int half = kcnt >> 1;                 // equal halves (even, >= 2)
    const int s0 = g ? half : 0;

    const f16* Abase = vT + ((size_t)b * D_ + be) * S_;
    const f16* Bbase = sh + ((size_t)b * S_ + bq) * S_;
    char* myl = lds + (g << 14);
    f32x4 acc[4][4] = {};
#pragma unroll 1
    for (int i = 0; i < half; ++i) {
        const int k0 = klist[s0 + i];
        stage128x32(Abase + k0, S_, myl, tl);
        stage128x32(Bbase + k0, S_, myl + 8192, tl);
        __syncthreads();
        mma_chunk(myl, myl + 8192, wm, wn, lr, quad, acc);
        __syncthreads();
    }

    // deterministic half-K combine: g1 writes its partials, g0 adds.
    // layout: f32x4 slot = (w*16 + j*4 + i)*64 + lane  (16B/lane, linear)
    if (g == 1) {
#pragma unroll
        for (int j = 0; j < 4; ++j)
#pragma unroll
            for (int i = 0; i < 4; ++i)
                *(f32x4*)(lds + (((w * 16 + j * 4 + i) * 64 + lane) << 4)) = acc[i][j];
    }
    __syncthreads();
    if (g == 0) {
#pragma unroll
        for (int j = 0; j < 4; ++j) {
            const int q = bq + wn * 64 + j * 16 + lr;
            const float ssv = ss[b * S_ + q];
            const float scl = 1.0f / (C_SCALE * fmaxf(sqrtf(ssv) * OUT_SCALE, 1e-5f));
#pragma unroll
            for (int i = 0; i < 4; ++i) {
                const f32x4 other =
                    *(const f32x4*)(lds + (((w * 16 + j * 4 + i) * 64 + lane) << 4));
                const f32x4 sum = acc[i][j] + other;
                const int e4 = be + wm * 64 + i * 16 + quad * 4;
                const size_t o = ((size_t)b * S_ + q) * D_ + e4;
                f32x4 xnew;
                f16x4 hx;
#pragma unroll
                for (int r = 0; r < 4; ++r) {
                    xnew[r] = sum[r] * scl;
                    hx[r] = (f16)xnew[r];
                }
                f32x4 val = xnew;
                if (accum) { const f32x4 old = *(const f32x4*)(out + o); val = val + old; }
                *(f32x4*)(out + o) = val;
                if (wxh) *(f16x4*)(xh + o) = hx;
            }
        }
    }
}

// ---------------------------------------------------------------------------
// Workspace: xh @0 (16M), vT @16M (16M), sh @32M (32M), Wh @64M (2M),
//            ss  @66M (4 heads x 64K = 256K), flags @66M+256K (512B)
// ---------------------------------------------------------------------------
extern "C" void kernel_launch(void* const* d_in, const int* in_sizes, int n_in,
                              void* d_out, int out_size, void* d_ws, size_t ws_size,
                              hipStream_t stream) {
    const float* x0    = (const float*)d_in[0];
    const int*   etype = (const int*)d_in[2];
    const float* W     = (const float*)d_in[3];
    const float* bias  = (const float*)d_in[4];
    float* out = (float*)d_out;

    char* ws = (char*)d_ws;
    f16*   xh    = (f16*)(ws);
    f16*   vT    = (f16*)(ws + (16u << 20));
    f16*   sh    = (f16*)(ws + (32u << 20));
    f16*   Wh    = (f16*)(ws + (64u << 20));
    float* ssb   = (float*)(ws + (66u << 20));
    int*   flags = (int*)(ws + (66u << 20) + 262144);

    k_conv <<<8192, 256, 0, stream>>>(x0, xh);
    k_conv <<<1024, 256, 0, stream>>>(W, Wh);
    k_flags<<<1, 128, 0, stream>>>(etype, flags);
    // zero sh once: skipped (never-written) tiles must read as exact zeros;
    // the skip set is head-invariant so one memset covers all 4 heads.
    hipMemsetAsync(sh, 0, (size_t)32 << 20, stream);
    // zero all 4 per-head Sum(s^2) accumulators once.
    hipMemsetAsync(ssb, 0, 4 * (size_t)B_ * S_ * sizeof(float), stream);

    for (int h = 0; h < H_; ++h) {
        float* ss = ssb + (size_t)h * B_ * S_;
        k_vs <<<1536, 256, 0, stream>>>(xh, Wh + (size_t)h * D_ * D_,
                                        bias + (size_t)h * D_, vT,
                                        etype, flags, sh, ss);
        k_out<<<512, 512, 0, stream>>>(vT, sh, ss, flags, xh, out,
                                       h > 0, h < H_ - 1);
    }
}

// Round 9
// 363.412 us; speedup vs baseline: 1.1497x; 1.0000x over previous
//
#include <hip/hip_runtime.h>
#include <math.h>

#define B_ 16
#define S_ 1024
#define D_ 512
#define H_ 4
#define INV_TEMP 0.044194173824159216f   // 1/sqrt(512)
#define C_SCALE 0.00390625f              // 2^-8: keeps head-4 scores inside fp16 range
#define OUT_SCALE 256.0f

typedef _Float16 f16;
typedef _Float16 f16x8 __attribute__((ext_vector_type(8)));
typedef _Float16 f16x4 __attribute__((ext_vector_type(4)));
typedef float f32x4 __attribute__((ext_vector_type(4)));

#define AS1(p) ((const __attribute__((address_space(1))) void*)(p))
#define AS3(p) ((__attribute__((address_space(3))) void*)(p))
#define MFMA __builtin_amdgcn_mfma_f32_16x16x32_f16

// ---------------------------------------------------------------------------
// fp32 -> fp16 convert
// ---------------------------------------------------------------------------
__global__ __launch_bounds__(256)
void k_conv(const float* __restrict__ src, f16* __restrict__ dst)
{
    const int i = blockIdx.x * 256 + threadIdx.x;
    const float4 v = ((const float4*)src)[i];
    f16x4 h; h[0] = (f16)v.x; h[1] = (f16)v.y; h[2] = (f16)v.z; h[3] = (f16)v.w;
    ((f16x4*)dst)[i] = h;
}

// ---------------------------------------------------------------------------
// pad flags: flag[b*8+kt] = 1 iff any event_type[b, kt*128 .. kt*128+127]==0
// ---------------------------------------------------------------------------
__global__ __launch_bounds__(128)
void k_flags(const int* __restrict__ etype, int* __restrict__ flag)
{
    const int t = threadIdx.x;           // 128 = B_ * 8
    const int b = t >> 3, kt = t & 7;
    const int* p = etype + b * S_ + kt * 128;
    int any0 = 0;
#pragma unroll
    for (int i = 0; i < 128; i += 4) {
        const int4 v = *(const int4*)(p + i);
        any0 |= (v.x == 0) | (v.y == 0) | (v.z == 0) | (v.w == 0);
    }
    flag[t] = any0;
}

// ---------------------------------------------------------------------------
// m97-style staging/MMA core (proven round 2 — single buffer, 2 barriers per
// K-step). Schedule-lane verdict after rounds 3-7: explicit dbuf (dynamic or
// static) and 8-phase counted-vmcnt both regress or wedge at this scale —
// hipcc inserts its own vmcnt(0) around global_load_lds-aliasing LDS reads.
// Do not touch the sync structure.
// ---------------------------------------------------------------------------
__device__ __forceinline__ void stage128x32(const f16* __restrict__ src, int ld,
                                            char* lds0, int t)
{
    const f16* g0 = src + (size_t)(t >> 2) * ld + (t & 3) * 8;
    __builtin_amdgcn_global_load_lds(AS1(g0), AS3(lds0 + t * 16), 16, 0, 0);
    const f16* g1 = g0 + (size_t)64 * ld;
    __builtin_amdgcn_global_load_lds(AS1(g1), AS3(lds0 + 4096 + t * 16), 16, 0, 0);
}

__device__ __forceinline__ void mma_chunk(const char* ldsA, const char* ldsB,
                                          int wm, int wn, int lr, int quad,
                                          f32x4 (*acc)[4])
{
    f16x8 af[4], bf[4];
#pragma unroll
    for (int i = 0; i < 4; ++i)
        af[i] = *(const f16x8*)(ldsA + ((wm * 64 + i * 16 + lr) * 32 + quad * 8) * 2);
#pragma unroll
    for (int j = 0; j < 4; ++j)
        bf[j] = *(const f16x8*)(ldsB + ((wn * 64 + j * 16 + lr) * 32 + quad * 8) * 2);
#pragma unroll
    for (int i = 0; i < 4; ++i)
#pragma unroll
        for (int j = 0; j < 4; ++j)
            acc[i][j] = MFMA(af[i], bf[j], acc[i][j], 0, 0, 0);
}

__device__ __forceinline__ void gemm_core(const f16* A, int ldA, const f16* Bm, int ldB,
                                          int K, char* lds, int t, int wm, int wn,
                                          int lr, int quad, f32x4 (*acc)[4])
{
    for (int k0 = 0; k0 < K; k0 += 32) {
        stage128x32(A + k0, ldA, lds, t);
        stage128x32(Bm + k0, ldB, lds + 8192, t);
        __syncthreads();
        mma_chunk(lds, lds + 8192, wm, wn, lr, quad, acc);
        __syncthreads();
    }
}

// ===========================================================================
// Merged per-head producer kernel (exact round-2 version, proven):
//   blocks [0,1024): scores (~44% early-exit) + fused Sum(s^2) via atomics
//   blocks [1024,1536): vT = ELU(x @ W^T + b)^T stored [B][D][S] fp16
// NOTE: sh is NOT pre-zeroed. Safe: k_out's klist reads exactly the tiles
// written here (same predicate), and ss comes from atomics over computed
// tiles only — skipped sh regions are never read by anyone.
// ===========================================================================
__global__ __launch_bounds__(256)
void k_vs(const f16* __restrict__ xh, const f16* __restrict__ Wh,
          const float* __restrict__ bias, f16* __restrict__ vT,
          const int* __restrict__ etype, const int* __restrict__ flag,
          f16* __restrict__ sh, float* __restrict__ ss)
{
    __shared__ __align__(16) char lds[16384];
    const int t = threadIdx.x;
    const int w = t >> 6, lane = t & 63, lr = lane & 15, quad = lane >> 4;
    const int wm = w & 1, wn = w >> 1;

    if (blockIdx.x < 1024) {
        // ---------------- scores ----------------
        const int i0 = blockIdx.x;
        const int xcd = i0 & 7, j0 = i0 >> 3;          // j0 in [0,128)
        const int b = 2 * xcd + (j0 & 1);
        const int tile = j0 >> 1;                      // [0,64)
        const int bk = (tile & 7) * 128;               // keys (M)
        const int bq = (tile >> 3) * 128;              // queries (N)
        // fully-masked tile: exact zero; never computed, never written,
        // never read downstream (klist skips it); ss contribution is 0.
        if (bk < bq && !flag[b * 8 + (bk >> 7)]) return;

        const f16* xb = xh + (size_t)b * S_ * D_;
        f32x4 acc[4][4] = {};
        gemm_core(xb + (size_t)bk * D_, D_, xb + (size_t)bq * D_, D_, D_,
                  lds, t, wm, wn, lr, quad, acc);
        const float sc = INV_TEMP * C_SCALE;
        float ssq[4] = {0.0f, 0.0f, 0.0f, 0.0f};
#pragma unroll
        for (int i = 0; i < 4; ++i) {
            const int k4 = bk + wm * 64 + i * 16 + quad * 4;
            const int4 et = *(const int4*)(etype + b * S_ + k4);
            const int ev[4] = {et.x, et.y, et.z, et.w};
#pragma unroll
            for (int j = 0; j < 4; ++j) {
                const int q = bq + wn * 64 + j * 16 + lr;
                f16x4 hv;
#pragma unroll
                for (int r = 0; r < 4; ++r) {
                    const bool keep = ((k4 + r) > q) || (ev[r] == 0);
                    hv[r] = (f16)(keep ? acc[i][j][r] * sc : 0.0f);
                    const float fv = (float)hv[r];
                    ssq[j] += fv * fv;               // sum of squares of STORED fp16
                }
                *(f16x4*)(sh + ((size_t)b * S_ + q) * S_ + k4) = hv;
            }
        }
#pragma unroll
        for (int j = 0; j < 4; ++j) {
            float v = ssq[j];
            v += __shfl_xor(v, 16, 64);
            v += __shfl_xor(v, 32, 64);
            if (quad == 0) {
                const int q = bq + wn * 64 + j * 16 + lr;
                atomicAdd(ss + b * S_ + q, v);
            }
        }
    } else {
        // ---------------- vT = ELU(x @ W^T + b)^T ----------------
        const int idx = blockIdx.x - 1024;
        const int bm = (idx & 127) * 128;              // rows of x (B*S)
        const int bn = (idx >> 7) * 128;               // output features e
        f32x4 acc[4][4] = {};
        gemm_core(xh + (size_t)bm * D_, D_, Wh + (size_t)bn * D_, D_, D_,
                  lds, t, wm, wn, lr, quad, acc);
#pragma unroll
        for (int j = 0; j < 4; ++j) {
            const int e = bn + wn * 64 + j * 16 + lr;
            const float be = bias[e];
#pragma unroll
            for (int i = 0; i < 4; ++i) {
                const int m = bm + wm * 64 + i * 16 + quad * 4;
                const int batch = m >> 10, s = m & 1023;
                f16x4 hv;
#pragma unroll
                for (int r = 0; r < 4; ++r) {
                    float z = acc[i][j][r] + be;
                    z = (z > 0.0f) ? z : (expf(z) - 1.0f);
                    hv[r] = (f16)z;
                }
                *(f16x4*)(vT + ((size_t)batch * D_ + e) * S_ + s) = hv;
            }
        }
    }
}

// ===========================================================================
// k_out: 512 blocks x 512 thr (8 waves), two 4-wave K-half groups (proven
// round 8). Epilogue variants (host-selected):
//   big mode, h<3 : write per-head fp16 x-buffer only (no out traffic)
//   big mode, h==3: out = xh0 + xh1 + xh2 + xnew (single fp32 write)
//   fallback      : round-8 behavior (fp32 out RMW + xh write)
// ===========================================================================
__global__ __launch_bounds__(512)
void k_out(const f16* __restrict__ vT, const f16* __restrict__ sh,
           const float* __restrict__ ss, const int* __restrict__ flag,
           f16* __restrict__ xh_w,
           const f16* __restrict__ xs0, const f16* __restrict__ xs1,
           const f16* __restrict__ xs2,
           float* __restrict__ out, const int accum, const int wout)
{
    __shared__ __align__(16) char lds[65536];   // staging g0 @0, g1 @16384; combine reuses [0,64K)
    __shared__ int klist[32];
    __shared__ int kcnt;
    const int t = threadIdx.x;
    const int g = t >> 8;                       // K-half group
    const int tl = t & 255;                     // thread id within group
    const int w = tl >> 6, lane = tl & 63, lr = lane & 15, quad = lane >> 4;
    const int wm = w & 1, wn = w >> 1;
    const int i0 = blockIdx.x;
    const int xcd = i0 & 7, j0 = i0 >> 3;       // j0 in [0,64)
    const int b = 2 * xcd + (j0 & 1);
    const int tile = j0 >> 1;                   // [0,32)
    const int be = (tile & 3) * 128;            // e (M), fastest
    const int bq = (tile >> 2) * 128;           // q (N)
    const int qt = bq >> 7;

    if (t == 0) {
        int n = 0;
        for (int kc = 0; kc < 8; ++kc)
            if (kc >= qt || flag[b * 8 + kc]) { // kept chunk
                const int kb = kc * 128;
                klist[n] = kb; klist[n + 1] = kb + 32;
                klist[n + 2] = kb + 64; klist[n + 3] = kb + 96;
                n += 4;
            }
        kcnt = n;                               // multiple of 4, >= 4
    }
    __syncthreads();
    const int half = kcnt >> 1;                 // equal halves (even, >= 2)
    const int s0 = g ? half : 0;

    const f16* Abase = vT + ((size_t)b * D_ + be) * S_;
    const f16* Bbase = sh + ((size_t)b * S_ + bq) * S_;
    char* myl = lds + (g << 14);
    f32x4 acc[4][4] = {};
#pragma unroll 1
    for (int i = 0; i < half; ++i) {
        const int k0 = klist[s0 + i];
        stage128x32(Abase + k0, S_, myl, tl);
        stage128x32(Bbase + k0, S_, myl + 8192, tl);
        __syncthreads();
        mma_chunk(myl, myl + 8192, wm, wn, lr, quad, acc);
        __syncthreads();
    }

    // deterministic half-K combine: g1 writes its partials, g0 adds.
    if (g == 1) {
#pragma unroll
        for (int j = 0; j < 4; ++j)
#pragma unroll
            for (int i = 0; i < 4; ++i)
                *(f32x4*)(lds + (((w * 16 + j * 4 + i) * 64 + lane) << 4)) = acc[i][j];
    }
    __syncthreads();
    if (g == 0) {
#pragma unroll
        for (int j = 0; j < 4; ++j) {
            const int q = bq + wn * 64 + j * 16 + lr;
            const float ssv = ss[b * S_ + q];
            const float scl = 1.0f / (C_SCALE * fmaxf(sqrtf(ssv) * OUT_SCALE, 1e-5f));
#pragma unroll
            for (int i = 0; i < 4; ++i) {
                const f32x4 other =
                    *(const f32x4*)(lds + (((w * 16 + j * 4 + i) * 64 + lane) << 4));
                const f32x4 sum = acc[i][j] + other;
                const int e4 = be + wm * 64 + i * 16 + quad * 4;
                const size_t o = ((size_t)b * S_ + q) * D_ + e4;
                f32x4 val;
                f16x4 hx;
#pragma unroll
                for (int r = 0; r < 4; ++r) {
                    val[r] = sum[r] * scl;
                    hx[r] = (f16)val[r];
                }
                if (xh_w) *(f16x4*)(xh_w + o) = hx;
                if (xs0) {                      // final head: sum fp16 partials
                    const f16x4 a0 = *(const f16x4*)(xs0 + o);
                    const f16x4 a1 = *(const f16x4*)(xs1 + o);
                    const f16x4 a2 = *(const f16x4*)(xs2 + o);
#pragma unroll
                    for (int r = 0; r < 4; ++r)
                        val[r] += (float)a0[r] + (float)a1[r] + (float)a2[r];
                }
                if (wout) {
                    f32x4 v2 = val;
                    if (accum) { const f32x4 old = *(const f32x4*)(out + o); v2 = v2 + old; }
                    *(f32x4*)(out + o) = v2;
                }
            }
        }
    }
}

// ---------------------------------------------------------------------------
// Workspace (big mode, ~100.3 MB):
//   xA @0 (16M: conv output, then reused as xh0), vT @16M (16M),
//   sh @32M (32M), Wh @64M (2M), ss @66M (256K), flags @66M+256K,
//   xB @68M (16M: xh1), xC @84M (16M: xh2)
// Fallback (< 101 MB ws): round-8 layout/behavior (xB=xC=xA, fp32 out RMW).
// ---------------------------------------------------------------------------
extern "C" void kernel_launch(void* const* d_in, const int* in_sizes, int n_in,
                              void* d_out, int out_size, void* d_ws, size_t ws_size,
                              hipStream_t stream) {
    const float* x0    = (const float*)d_in[0];
    const int*   etype = (const int*)d_in[2];
    const float* W     = (const float*)d_in[3];
    const float* bias  = (const float*)d_in[4];
    float* out = (float*)d_out;

    char* ws = (char*)d_ws;
    f16*   xA    = (f16*)(ws);
    f16*   vT    = (f16*)(ws + (16u << 20));
    f16*   sh    = (f16*)(ws + (32u << 20));
    f16*   Wh    = (f16*)(ws + (64u << 20));
    float* ssb   = (float*)(ws + (66u << 20));
    int*   flags = (int*)(ws + (66u << 20) + 262144);

    const bool big = ws_size >= ((size_t)101 << 20);
    f16* xB = big ? (f16*)(ws + (68u << 20)) : xA;
    f16* xC = big ? (f16*)(ws + (84u << 20)) : xA;

    k_conv <<<8192, 256, 0, stream>>>(x0, xA);
    k_conv <<<1024, 256, 0, stream>>>(W, Wh);
    k_flags<<<1, 128, 0, stream>>>(etype, flags);
    // zero all 4 per-head Sum(s^2) accumulators once (sh needs NO zeroing:
    // skipped tiles are never read — klist matches the write predicate).
    hipMemsetAsync(ssb, 0, 4 * (size_t)B_ * S_ * sizeof(float), stream);

    // per-head k_vs input and k_out fp16 destination
    f16* xin[H_]  = {xA, xA, xB, xC};
    f16* xdst[H_] = {xA, xB, xC, nullptr};

    for (int h = 0; h < H_; ++h) {
        float* ss = ssb + (size_t)h * B_ * S_;
        k_vs <<<1536, 256, 0, stream>>>(xin[h], Wh + (size_t)h * D_ * D_,
                                        bias + (size_t)h * D_, vT,
                                        etype, flags, sh, ss);
        if (big) {
            const bool last = (h == H_ - 1);
            k_out<<<512, 512, 0, stream>>>(vT, sh, ss, flags, xdst[h],
                                           last ? xA : nullptr,
                                           last ? xB : nullptr,
                                           last ? xC : nullptr,
                                           out, 0, last ? 1 : 0);
        } else {
            k_out<<<512, 512, 0, stream>>>(vT, sh, ss, flags,
                                           (h < H_ - 1) ? xA : nullptr,
                                           nullptr, nullptr, nullptr,
                                           out, h > 0, 1);
        }
    }
}

// Round 10
// 350.443 us; speedup vs baseline: 1.1922x; 1.0370x over previous
//
#include <hip/hip_runtime.h>
#include <math.h>

#define B_ 16
#define S_ 1024
#define D_ 512
#define H_ 4
#define INV_TEMP 0.044194173824159216f   // 1/sqrt(512)
#define C_SCALE 0.00390625f              // 2^-8: keeps head-4 scores inside fp16 range
#define OUT_SCALE 256.0f

typedef _Float16 f16;
typedef _Float16 f16x8 __attribute__((ext_vector_type(8)));
typedef _Float16 f16x4 __attribute__((ext_vector_type(4)));
typedef float f32x4 __attribute__((ext_vector_type(4)));

#define AS1(p) ((const __attribute__((address_space(1))) void*)(p))
#define AS3(p) ((__attribute__((address_space(3))) void*)(p))
#define MFMA __builtin_amdgcn_mfma_f32_16x16x32_f16

// ---------------------------------------------------------------------------
// fp32 -> fp16 convert
// ---------------------------------------------------------------------------
__global__ __launch_bounds__(256)
void k_conv(const float* __restrict__ src, f16* __restrict__ dst)
{
    const int i = blockIdx.x * 256 + threadIdx.x;
    const float4 v = ((const float4*)src)[i];
    f16x4 h; h[0] = (f16)v.x; h[1] = (f16)v.y; h[2] = (f16)v.z; h[3] = (f16)v.w;
    ((f16x4*)dst)[i] = h;
}

// ---------------------------------------------------------------------------
// pad flags: flag[b*8+kt] = 1 iff any event_type[b, kt*128 .. kt*128+127]==0
// ---------------------------------------------------------------------------
__global__ __launch_bounds__(128)
void k_flags(const int* __restrict__ etype, int* __restrict__ flag)
{
    const int t = threadIdx.x;           // 128 = B_ * 8
    const int b = t >> 3, kt = t & 7;
    const int* p = etype + b * S_ + kt * 128;
    int any0 = 0;
#pragma unroll
    for (int i = 0; i < 128; i += 4) {
        const int4 v = *(const int4*)(p + i);
        any0 |= (v.x == 0) | (v.y == 0) | (v.z == 0) | (v.w == 0);
    }
    flag[t] = any0;
}

// ---------------------------------------------------------------------------
// BK=64 staging/MMA core. Same proven 2-barrier-per-period sync structure as
// the m97 loop (rounds 3-7 established: do NOT touch barrier semantics);
// only the period size doubles (16->8 periods for K=512), halving barrier
// drains per MFMA. LDS tile [128][64] f16, 16 KB, XOR-swizzled:
//   slot s (16B units) of row r holds global col-group (s ^ (r&7))
// applied via pre-swizzled GLOBAL source (linear LDS dest, rule #21) and
// the matching XOR on the ds_read side. Without this, a 128B-row-stride
// layout is a 16-way bank conflict (G4). Verified-zero-conflict pattern
// (round 7). K-contraction order preserved exactly: ascending 64-steps,
// kk=0,1 ascending inside -> bitwise-identical to the BK=32 version.
// ---------------------------------------------------------------------------
__device__ __forceinline__ void stage128x64(const f16* __restrict__ src, int ld,
                                            char* lds0, int t)
{
    const int r = t >> 3;                         // rows 0..31 (+32j below)
    const int c = ((t & 7) ^ (r & 7)) << 3;       // pre-swizzled col-group
    const f16* g = src + (size_t)r * ld + c;
#pragma unroll
    for (int j = 0; j < 4; ++j)                   // (r+32j)&7 == r&7
        __builtin_amdgcn_global_load_lds(AS1(g + (size_t)(32 * j) * ld),
                                         AS3(lds0 + j * 4096 + t * 16), 16, 0, 0);
}

__device__ __forceinline__ void mma64(const char* ldsA, const char* ldsB,
                                      int wm, int wn, int lr, int quad,
                                      f32x4 (*acc)[4])
{
#pragma unroll
    for (int kk = 0; kk < 2; ++kk) {
        f16x8 af[4], bf[4];
#pragma unroll
        for (int i = 0; i < 4; ++i) {
            const int row = wm * 64 + i * 16 + lr;
            af[i] = *(const f16x8*)(ldsA + (row << 7) +
                                    ((((kk << 2) + quad) ^ (row & 7)) << 4));
        }
#pragma unroll
        for (int j = 0; j < 4; ++j) {
            const int row = wn * 64 + j * 16 + lr;
            bf[j] = *(const f16x8*)(ldsB + (row << 7) +
                                    ((((kk << 2) + quad) ^ (row & 7)) << 4));
        }
#pragma unroll
        for (int i = 0; i < 4; ++i)
#pragma unroll
            for (int j = 0; j < 4; ++j)
                acc[i][j] = MFMA(af[i], bf[j], acc[i][j], 0, 0, 0);
    }
}

// diag: A and B are the same rows (scores diagonal tiles) -> stage once,
// alias B's buffer. Block-uniform flag; bitwise-identical result.
__device__ __forceinline__ void gemm_core64(const f16* A, int ldA,
                                            const f16* Bm, int ldB,
                                            int K, char* lds, int t,
                                            int wm, int wn, int lr, int quad,
                                            f32x4 (*acc)[4], bool diag)
{
    char* lb = diag ? lds : lds + 16384;
    for (int k0 = 0; k0 < K; k0 += 64) {
        stage128x64(A + k0, ldA, lds, t);
        if (!diag) stage128x64(Bm + k0, ldB, lb, t);
        __syncthreads();
        mma64(lds, lb, wm, wn, lr, quad, acc);
        __syncthreads();
    }
}

// ===========================================================================
// Merged per-head producer kernel (round-2 mapping, BK=64 core):
//   blocks [0,1024): scores (~44% early-exit) + fused Sum(s^2) via atomics
//   blocks [1024,1536): vT = ELU(x @ W^T + b)^T stored [B][D][S] fp16
// sh is NOT pre-zeroed: k_out's klist reads exactly the tiles written here.
// ===========================================================================
__global__ __launch_bounds__(256)
void k_vs(const f16* __restrict__ xh, const f16* __restrict__ Wh,
          const float* __restrict__ bias, f16* __restrict__ vT,
          const int* __restrict__ etype, const int* __restrict__ flag,
          f16* __restrict__ sh, float* __restrict__ ss)
{
    __shared__ __align__(16) char lds[32768];
    const int t = threadIdx.x;
    const int w = t >> 6, lane = t & 63, lr = lane & 15, quad = lane >> 4;
    const int wm = w & 1, wn = w >> 1;

    if (blockIdx.x < 1024) {
        // ---------------- scores ----------------
        const int i0 = blockIdx.x;
        const int xcd = i0 & 7, j0 = i0 >> 3;          // j0 in [0,128)
        const int b = 2 * xcd + (j0 & 1);
        const int tile = j0 >> 1;                      // [0,64)
        const int bk = (tile & 7) * 128;               // keys (M)
        const int bq = (tile >> 3) * 128;              // queries (N)
        // fully-masked tile: exact zero; never computed, never written,
        // never read downstream (klist skips it); ss contribution is 0.
        if (bk < bq && !flag[b * 8 + (bk >> 7)]) return;

        const f16* xb = xh + (size_t)b * S_ * D_;
        f32x4 acc[4][4] = {};
        gemm_core64(xb + (size_t)bk * D_, D_, xb + (size_t)bq * D_, D_, D_,
                    lds, t, wm, wn, lr, quad, acc, bk == bq);
        const float sc = INV_TEMP * C_SCALE;
        float ssq[4] = {0.0f, 0.0f, 0.0f, 0.0f};
#pragma unroll
        for (int i = 0; i < 4; ++i) {
            const int k4 = bk + wm * 64 + i * 16 + quad * 4;
            const int4 et = *(const int4*)(etype + b * S_ + k4);
            const int ev[4] = {et.x, et.y, et.z, et.w};
#pragma unroll
            for (int j = 0; j < 4; ++j) {
                const int q = bq + wn * 64 + j * 16 + lr;
                f16x4 hv;
#pragma unroll
                for (int r = 0; r < 4; ++r) {
                    const bool keep = ((k4 + r) > q) || (ev[r] == 0);
                    hv[r] = (f16)(keep ? acc[i][j][r] * sc : 0.0f);
                    const float fv = (float)hv[r];
                    ssq[j] += fv * fv;               // sum of squares of STORED fp16
                }
                *(f16x4*)(sh + ((size_t)b * S_ + q) * S_ + k4) = hv;
            }
        }
#pragma unroll
        for (int j = 0; j < 4; ++j) {
            float v = ssq[j];
            v += __shfl_xor(v, 16, 64);
            v += __shfl_xor(v, 32, 64);
            if (quad == 0) {
                const int q = bq + wn * 64 + j * 16 + lr;
                atomicAdd(ss + b * S_ + q, v);
            }
        }
    } else {
        // ---------------- vT = ELU(x @ W^T + b)^T ----------------
        const int idx = blockIdx.x - 1024;
        const int bm = (idx & 127) * 128;              // rows of x (B*S)
        const int bn = (idx >> 7) * 128;               // output features e
        f32x4 acc[4][4] = {};
        gemm_core64(xh + (size_t)bm * D_, D_, Wh + (size_t)bn * D_, D_, D_,
                    lds, t, wm, wn, lr, quad, acc, false);
#pragma unroll
        for (int j = 0; j < 4; ++j) {
            const int e = bn + wn * 64 + j * 16 + lr;
            const float be = bias[e];
#pragma unroll
            for (int i = 0; i < 4; ++i) {
                const int m = bm + wm * 64 + i * 16 + quad * 4;
                const int batch = m >> 10, s = m & 1023;
                f16x4 hv;
#pragma unroll
                for (int r = 0; r < 4; ++r) {
                    float z = acc[i][j][r] + be;
                    z = (z > 0.0f) ? z : (expf(z) - 1.0f);
                    hv[r] = (f16)z;
                }
                *(f16x4*)(vT + ((size_t)batch * D_ + e) * S_ + s) = hv;
            }
        }
    }
}

// ===========================================================================
// k_out: 512 blocks x 512 thr (8 waves), two 4-wave K-half groups (proven
// round 8), BK=64 core. klist pairs (even index i, i+1) are always a
// contiguous 64-col run (each kept chunk contributes 4 consecutive 32-offs).
// Epilogue variants (host-selected):
//   big mode, h<3 : write per-head fp16 x-buffer only (no out traffic)
//   big mode, h==3: out = xh0 + xh1 + xh2 + xnew (single fp32 write)
//   fallback      : fp32 out RMW + xh write
// ===========================================================================
__global__ __launch_bounds__(512)
void k_out(const f16* __restrict__ vT, const f16* __restrict__ sh,
           const float* __restrict__ ss, const int* __restrict__ flag,
           f16* __restrict__ xh_w,
           const f16* __restrict__ xs0, const f16* __restrict__ xs1,
           const f16* __restrict__ xs2,
           float* __restrict__ out, const int accum, const int wout)
{
    __shared__ __align__(16) char lds[65536];   // g0 @0 (A,B 16K each), g1 @32768; combine reuses all
    __shared__ int klist[32];
    __shared__ int kcnt;
    const int t = threadIdx.x;
    const int g = t >> 8;                       // K-half group
    const int tl = t & 255;                     // thread id within group
    const int w = tl >> 6, lane = tl & 63, lr = lane & 15, quad = lane >> 4;
    const int wm = w & 1, wn = w >> 1;
    const int i0 = blockIdx.x;
    const int xcd = i0 & 7, j0 = i0 >> 3;       // j0 in [0,64)
    const int b = 2 * xcd + (j0 & 1);
    const int tile = j0 >> 1;                   // [0,32)
    const int be = (tile & 3) * 128;            // e (M), fastest
    const int bq = (tile >> 2) * 128;           // q (N)
    const int qt = bq >> 7;

    if (t == 0) {
        int n = 0;
        for (int kc = 0; kc < 8; ++kc)
            if (kc >= qt || flag[b * 8 + kc]) { // kept chunk
                const int kb = kc * 128;
                klist[n] = kb; klist[n + 1] = kb + 32;
                klist[n + 2] = kb + 64; klist[n + 3] = kb + 96;
                n += 4;
            }
        kcnt = n;                               // multiple of 4, >= 4
    }
    __syncthreads();
    const int half = kcnt >> 1;                 // even (kcnt mult of 4)
    const int s0 = g ? half : 0;

    const f16* Abase = vT + ((size_t)b * D_ + be) * S_;
    const f16* Bbase = sh + ((size_t)b * S_ + bq) * S_;
    char* myl = lds + (g << 15);
    f32x4 acc[4][4] = {};
#pragma unroll 1
    for (int i = 0; i < half; i += 2) {         // 64 contiguous cols per step
        const int k0 = klist[s0 + i];
        stage128x64(Abase + k0, S_, myl, tl);
        stage128x64(Bbase + k0, S_, myl + 16384, tl);
        __syncthreads();
        mma64(myl, myl + 16384, wm, wn, lr, quad, acc);
        __syncthreads();
    }

    // deterministic half-K combine: g1 writes its partials, g0 adds.
    if (g == 1) {
#pragma unroll
        for (int j = 0; j < 4; ++j)
#pragma unroll
            for (int i = 0; i < 4; ++i)
                *(f32x4*)(lds + (((w * 16 + j * 4 + i) * 64 + lane) << 4)) = acc[i][j];
    }
    __syncthreads();
    if (g == 0) {
#pragma unroll
        for (int j = 0; j < 4; ++j) {
            const int q = bq + wn * 64 + j * 16 + lr;
            const float ssv = ss[b * S_ + q];
            const float scl = 1.0f / (C_SCALE * fmaxf(sqrtf(ssv) * OUT_SCALE, 1e-5f));
#pragma unroll
            for (int i = 0; i < 4; ++i) {
                const f32x4 other =
                    *(const f32x4*)(lds + (((w * 16 + j * 4 + i) * 64 + lane) << 4));
                const f32x4 sum = acc[i][j] + other;
                const int e4 = be + wm * 64 + i * 16 + quad * 4;
                const size_t o = ((size_t)b * S_ + q) * D_ + e4;
                f32x4 val;
                f16x4 hx;
#pragma unroll
                for (int r = 0; r < 4; ++r) {
                    val[r] = sum[r] * scl;
                    hx[r] = (f16)val[r];
                }
                if (xh_w) *(f16x4*)(xh_w + o) = hx;
                if (xs0) {                      // final head: sum fp16 partials
                    const f16x4 a0 = *(const f16x4*)(xs0 + o);
                    const f16x4 a1 = *(const f16x4*)(xs1 + o);
                    const f16x4 a2 = *(const f16x4*)(xs2 + o);
#pragma unroll
                    for (int r = 0; r < 4; ++r)
                        val[r] += (float)a0[r] + (float)a1[r] + (float)a2[r];
                }
                if (wout) {
                    f32x4 v2 = val;
                    if (accum) { const f32x4 old = *(const f32x4*)(out + o); v2 = v2 + old; }
                    *(f32x4*)(out + o) = v2;
                }
            }
        }
    }
}

// ---------------------------------------------------------------------------
// Workspace (big mode, ~100.3 MB):
//   xA @0 (16M: conv output, then reused as xh0), vT @16M (16M),
//   sh @32M (32M), Wh @64M (2M), ss @66M (256K), flags @66M+256K,
//   xB @68M (16M: xh1), xC @84M (16M: xh2)
// Fallback (< 101 MB ws): xB=xC=xA, fp32 out RMW.
// ---------------------------------------------------------------------------
extern "C" void kernel_launch(void* const* d_in, const int* in_sizes, int n_in,
                              void* d_out, int out_size, void* d_ws, size_t ws_size,
                              hipStream_t stream) {
    const float* x0    = (const float*)d_in[0];
    const int*   etype = (const int*)d_in[2];
    const float* W     = (const float*)d_in[3];
    const float* bias  = (const float*)d_in[4];
    float* out = (float*)d_out;

    char* ws = (char*)d_ws;
    f16*   xA    = (f16*)(ws);
    f16*   vT    = (f16*)(ws + (16u << 20));
    f16*   sh    = (f16*)(ws + (32u << 20));
    f16*   Wh    = (f16*)(ws + (64u << 20));
    float* ssb   = (float*)(ws + (66u << 20));
    int*   flags = (int*)(ws + (66u << 20) + 262144);

    const bool big = ws_size >= ((size_t)101 << 20);
    f16* xB = big ? (f16*)(ws + (68u << 20)) : xA;
    f16* xC = big ? (f16*)(ws + (84u << 20)) : xA;

    k_conv <<<8192, 256, 0, stream>>>(x0, xA);
    k_conv <<<1024, 256, 0, stream>>>(W, Wh);
    k_flags<<<1, 128, 0, stream>>>(etype, flags);
    // zero all 4 per-head Sum(s^2) accumulators once (sh needs NO zeroing:
    // skipped tiles are never read — klist matches the write predicate).
    hipMemsetAsync(ssb, 0, 4 * (size_t)B_ * S_ * sizeof(float), stream);

    // per-head k_vs input and k_out fp16 destination
    f16* xin[H_]  = {xA, xA, xB, xC};
    f16* xdst[H_] = {xA, xB, xC, nullptr};

    for (int h = 0; h < H_; ++h) {
        float* ss = ssb + (size_t)h * B_ * S_;
        k_vs <<<1536, 256, 0, stream>>>(xin[h], Wh + (size_t)h * D_ * D_,
                                        bias + (size_t)h * D_, vT,
                                        etype, flags, sh, ss);
        if (big) {
            const bool last = (h == H_ - 1);
            k_out<<<512, 512, 0, stream>>>(vT, sh, ss, flags, xdst[h],
                                           last ? xA : nullptr,
                                           last ? xB : nullptr,
                                           last ? xC : nullptr,
                                           out, 0, last ? 1 : 0);
        } else {
            k_out<<<512, 512, 0, stream>>>(vT, sh, ss, flags,
                                           (h < H_ - 1) ? xA : nullptr,
                                           nullptr, nullptr, nullptr,
                                           out, h > 0, 1);
        }
    }
}

// Round 12
// 339.102 us; speedup vs baseline: 1.2321x; 1.0334x over previous
//
#include <hip/hip_runtime.h>
#include <math.h>

#define B_ 16
#define S_ 1024
#define D_ 512
#define H_ 4
#define INV_TEMP 0.044194173824159216f   // 1/sqrt(512)
#define C_SCALE 0.00390625f              // 2^-8: keeps head-4 scores inside fp16 range
#define OUT_SCALE 256.0f

typedef _Float16 f16;
typedef _Float16 f16x8 __attribute__((ext_vector_type(8)));
typedef _Float16 f16x4 __attribute__((ext_vector_type(4)));
typedef float f32x4 __attribute__((ext_vector_type(4)));

#define AS1(p) ((const __attribute__((address_space(1))) void*)(p))
#define AS3(p) ((__attribute__((address_space(3))) void*)(p))
#define MFMA __builtin_amdgcn_mfma_f32_16x16x32_f16

// ===========================================================================
// Fused prologue (single launch, 9281 blocks x 256 thr):
//   [0,8192)    : x fp32 -> fp16            (8M float4)
//   [8192,9216) : W fp32 -> fp16            (256K float4)
//   9216        : pad flags (128 lanes)
//   [9217,9281) : zero the 4 per-head Sum(s^2) accumulators (16K float4)
// All outputs independent -> race-free by construction.
// ===========================================================================
__global__ __launch_bounds__(256)
void k_pre(const float* __restrict__ x0, f16* __restrict__ xh,
           const float* __restrict__ W, f16* __restrict__ Wh,
           const int* __restrict__ etype, int* __restrict__ flag,
           float* __restrict__ ssb)
{
    const int t = threadIdx.x;
    const int bi = blockIdx.x;
    if (bi < 8192) {
        const int i = bi * 256 + t;
        const float4 v = ((const float4*)x0)[i];
        f16x4 h; h[0] = (f16)v.x; h[1] = (f16)v.y; h[2] = (f16)v.z; h[3] = (f16)v.w;
        ((f16x4*)xh)[i] = h;
    } else if (bi < 9216) {
        const int i = (bi - 8192) * 256 + t;
        const float4 v = ((const float4*)W)[i];
        f16x4 h; h[0] = (f16)v.x; h[1] = (f16)v.y; h[2] = (f16)v.z; h[3] = (f16)v.w;
        ((f16x4*)Wh)[i] = h;
    } else if (bi == 9216) {
        if (t < 128) {
            const int b = t >> 3, kt = t & 7;
            const int* p = etype + b * S_ + kt * 128;
            int any0 = 0;
#pragma unroll
            for (int i = 0; i < 128; i += 4) {
                const int4 v = *(const int4*)(p + i);
                any0 |= (v.x == 0) | (v.y == 0) | (v.z == 0) | (v.w == 0);
            }
            flag[t] = any0;
        }
    } else {
        const int i = (bi - 9217) * 256 + t;     // 64 blocks cover 16K float4
        ((float4*)ssb)[i] = make_float4(0.f, 0.f, 0.f, 0.f);
    }
}

// ---------------------------------------------------------------------------
// BK=64 staging/MMA core (proven round 10). 2-barrier-per-period sync
// structure (rounds 3-7: do NOT touch barrier semantics). LDS tile [128][64]
// f16, 16 KB, XOR-swizzled: 16B slot s of row r holds global col-group
// (s ^ (r&7)); pre-swizzled GLOBAL source + matching XOR on ds_read
// (both-sides rule #21). Zero bank conflicts measured (round 10).
// K-contraction order: ascending 64-steps, kk=0,1 ascending inside.
// ---------------------------------------------------------------------------
__device__ __forceinline__ void stage128x64(const f16* __restrict__ src, int ld,
                                            char* lds0, int t)
{
    const int r = t >> 3;                         // rows 0..31 (+32j below)
    const int c = ((t & 7) ^ (r & 7)) << 3;       // pre-swizzled col-group
    const f16* g = src + (size_t)r * ld + c;
#pragma unroll
    for (int j = 0; j < 4; ++j)                   // (r+32j)&7 == r&7
        __builtin_amdgcn_global_load_lds(AS1(g + (size_t)(32 * j) * ld),
                                         AS3(lds0 + j * 4096 + t * 16), 16, 0, 0);
}

__device__ __forceinline__ void mma64(const char* ldsA, const char* ldsB,
                                      int wm, int wn, int lr, int quad,
                                      f32x4 (*acc)[4])
{
#pragma unroll
    for (int kk = 0; kk < 2; ++kk) {
        f16x8 af[4], bf[4];
#pragma unroll
        for (int i = 0; i < 4; ++i) {
            const int row = wm * 64 + i * 16 + lr;
            af[i] = *(const f16x8*)(ldsA + (row << 7) +
                                    ((((kk << 2) + quad) ^ (row & 7)) << 4));
        }
#pragma unroll
        for (int j = 0; j < 4; ++j) {
            const int row = wn * 64 + j * 16 + lr;
            bf[j] = *(const f16x8*)(ldsB + (row << 7) +
                                    ((((kk << 2) + quad) ^ (row & 7)) << 4));
        }
#pragma unroll
        for (int i = 0; i < 4; ++i)
#pragma unroll
            for (int j = 0; j < 4; ++j)
                acc[i][j] = MFMA(af[i], bf[j], acc[i][j], 0, 0, 0);
    }
}

// diag: A and B are the same rows (scores diagonal tiles) -> stage once,
// alias B's buffer. Block-uniform flag; bitwise-identical result.
__device__ __forceinline__ void gemm_core64(const f16* A, int ldA,
                                            const f16* Bm, int ldB,
                                            int K, char* lds, int t,
                                            int wm, int wn, int lr, int quad,
                                            f32x4 (*acc)[4], bool diag)
{
    char* lb = diag ? lds : lds + 16384;
    for (int k0 = 0; k0 < K; k0 += 64) {
        stage128x64(A + k0, ldA, lds, t);
        if (!diag) stage128x64(Bm + k0, ldB, lb, t);
        __syncthreads();
        mma64(lds, lb, wm, wn, lr, quad, acc);
        __syncthreads();
    }
}

// ===========================================================================
// Merged per-head producer kernel (round-10 version, unchanged):
//   blocks [0,1024): scores (~44% early-exit) + fused Sum(s^2) via atomics
//   blocks [1024,1536): vT = ELU(x @ W^T + b)^T stored [B][D][S] fp16
// sh is NOT pre-zeroed: k_out's klist reads exactly the tiles written here.
// ===========================================================================
__global__ __launch_bounds__(256)
void k_vs(const f16* __restrict__ xh, const f16* __restrict__ Wh,
          const float* __restrict__ bias, f16* __restrict__ vT,
          const int* __restrict__ etype, const int* __restrict__ flag,
          f16* __restrict__ sh, float* __restrict__ ss)
{
    __shared__ __align__(16) char lds[32768];
    const int t = threadIdx.x;
    const int w = t >> 6, lane = t & 63, lr = lane & 15, quad = lane >> 4;
    const int wm = w & 1, wn = w >> 1;

    if (blockIdx.x < 1024) {
        // ---------------- scores ----------------
        const int i0 = blockIdx.x;
        const int xcd = i0 & 7, j0 = i0 >> 3;          // j0 in [0,128)
        const int b = 2 * xcd + (j0 & 1);
        const int tile = j0 >> 1;                      // [0,64)
        const int bk = (tile & 7) * 128;               // keys (M)
        const int bq = (tile >> 3) * 128;              // queries (N)
        // fully-masked tile: exact zero; never computed, never written,
        // never read downstream (klist skips it); ss contribution is 0.
        if (bk < bq && !flag[b * 8 + (bk >> 7)]) return;

        const f16* xb = xh + (size_t)b * S_ * D_;
        f32x4 acc[4][4] = {};
        gemm_core64(xb + (size_t)bk * D_, D_, xb + (size_t)bq * D_, D_, D_,
                    lds, t, wm, wn, lr, quad, acc, bk == bq);
        const float sc = INV_TEMP * C_SCALE;
        float ssq[4] = {0.0f, 0.0f, 0.0f, 0.0f};
#pragma unroll
        for (int i = 0; i < 4; ++i) {
            const int k4 = bk + wm * 64 + i * 16 + quad * 4;
            const int4 et = *(const int4*)(etype + b * S_ + k4);
            const int ev[4] = {et.x, et.y, et.z, et.w};
#pragma unroll
            for (int j = 0; j < 4; ++j) {
                const int q = bq + wn * 64 + j * 16 + lr;
                f16x4 hv;
#pragma unroll
                for (int r = 0; r < 4; ++r) {
                    const bool keep = ((k4 + r) > q) || (ev[r] == 0);
                    hv[r] = (f16)(keep ? acc[i][j][r] * sc : 0.0f);
                    const float fv = (float)hv[r];
                    ssq[j] += fv * fv;               // sum of squares of STORED fp16
                }
                *(f16x4*)(sh + ((size_t)b * S_ + q) * S_ + k4) = hv;
            }
        }
#pragma unroll
        for (int j = 0; j < 4; ++j) {
            float v = ssq[j];
            v += __shfl_xor(v, 16, 64);
            v += __shfl_xor(v, 32, 64);
            if (quad == 0) {
                const int q = bq + wn * 64 + j * 16 + lr;
                atomicAdd(ss + b * S_ + q, v);
            }
        }
    } else {
        // ---------------- vT = ELU(x @ W^T + b)^T ----------------
        const int idx = blockIdx.x - 1024;
        const int bm = (idx & 127) * 128;              // rows of x (B*S)
        const int bn = (idx >> 7) * 128;               // output features e
        f32x4 acc[4][4] = {};
        gemm_core64(xh + (size_t)bm * D_, D_, Wh + (size_t)bn * D_, D_, D_,
                    lds, t, wm, wn, lr, quad, acc, false);
#pragma unroll
        for (int j = 0; j < 4; ++j) {
            const int e = bn + wn * 64 + j * 16 + lr;
            const float be = bias[e];
#pragma unroll
            for (int i = 0; i < 4; ++i) {
                const int m = bm + wm * 64 + i * 16 + quad * 4;
                const int batch = m >> 10, s = m & 1023;
                f16x4 hv;
#pragma unroll
                for (int r = 0; r < 4; ++r) {
                    float z = acc[i][j][r] + be;
                    z = (z > 0.0f) ? z : (expf(z) - 1.0f);
                    hv[r] = (f16)z;
                }
                *(f16x4*)(vT + ((size_t)batch * D_ + e) * S_ + s) = hv;
            }
        }
    }
}

// ===========================================================================
// k_out: EXACT round-10 proven version. 512 blocks x 512 thr (8 waves),
// two 4-wave K-half groups, BK=64 core, 128x128 tiles. klist pairs (even
// index i, i+1) are always a contiguous 64-col run. Deterministic combine:
// g1 -> LDS -> g0 adds. Epilogue variants (host-selected):
//   big mode, h<3 : write per-head fp16 x-buffer only (no out traffic)
//   big mode, h==3: out = xh0 + xh1 + xh2 + xnew (single fp32 write)
//   fallback      : fp32 out RMW + xh write
// ===========================================================================
__global__ __launch_bounds__(512)
void k_out(const f16* __restrict__ vT, const f16* __restrict__ sh,
           const float* __restrict__ ss, const int* __restrict__ flag,
           f16* __restrict__ xh_w,
           const f16* __restrict__ xs0, const f16* __restrict__ xs1,
           const f16* __restrict__ xs2,
           float* __restrict__ out, const int accum, const int wout)
{
    __shared__ __align__(16) char lds[65536];   // g0 @0 (A,B 16K each), g1 @32768; combine reuses all
    __shared__ int klist[32];
    __shared__ int kcnt;
    const int t = threadIdx.x;
    const int g = t >> 8;                       // K-half group
    const int tl = t & 255;                     // thread id within group
    const int w = tl >> 6, lane = tl & 63, lr = lane & 15, quad = lane >> 4;
    const int wm = w & 1, wn = w >> 1;
    const int i0 = blockIdx.x;
    const int xcd = i0 & 7, j0 = i0 >> 3;       // j0 in [0,64)
    const int b = 2 * xcd + (j0 & 1);
    const int tile = j0 >> 1;                   // [0,32)
    const int be = (tile & 3) * 128;            // e (M), fastest
    const int bq = (tile >> 2) * 128;           // q (N)
    const int qt = bq >> 7;

    if (t == 0) {
        int n = 0;
        for (int kc = 0; kc < 8; ++kc)
            if (kc >= qt || flag[b * 8 + kc]) { // kept chunk
                const int kb = kc * 128;
                klist[n] = kb; klist[n + 1] = kb + 32;
                klist[n + 2] = kb + 64; klist[n + 3] = kb + 96;
                n += 4;
            }
        kcnt = n;                               // multiple of 4, >= 4
    }
    __syncthreads();
    const int half = kcnt >> 1;                 // even (kcnt mult of 4)
    const int s0 = g ? half : 0;

    const f16* Abase = vT + ((size_t)b * D_ + be) * S_;
    const f16* Bbase = sh + ((size_t)b * S_ + bq) * S_;
    char* myl = lds + (g << 15);
    f32x4 acc[4][4] = {};
#pragma unroll 1
    for (int i = 0; i < half; i += 2) {         // 64 contiguous cols per step
        const int k0 = klist[s0 + i];
        stage128x64(Abase + k0, S_, myl, tl);
        stage128x64(Bbase + k0, S_, myl + 16384, tl);
        __syncthreads();
        mma64(myl, myl + 16384, wm, wn, lr, quad, acc);
        __syncthreads();
    }

    // deterministic half-K combine: g1 writes its partials, g0 adds.
    if (g == 1) {
#pragma unroll
        for (int j = 0; j < 4; ++j)
#pragma unroll
            for (int i = 0; i < 4; ++i)
                *(f32x4*)(lds + (((w * 16 + j * 4 + i) * 64 + lane) << 4)) = acc[i][j];
    }
    __syncthreads();
    if (g == 0) {
#pragma unroll
        for (int j = 0; j < 4; ++j) {
            const int q = bq + wn * 64 + j * 16 + lr;
            const float ssv = ss[b * S_ + q];
            const float scl = 1.0f / (C_SCALE * fmaxf(sqrtf(ssv) * OUT_SCALE, 1e-5f));
#pragma unroll
            for (int i = 0; i < 4; ++i) {
                const f32x4 other =
                    *(const f32x4*)(lds + (((w * 16 + j * 4 + i) * 64 + lane) << 4));
                const f32x4 sum = acc[i][j] + other;
                const int e4 = be + wm * 64 + i * 16 + quad * 4;
                const size_t o = ((size_t)b * S_ + q) * D_ + e4;
                f32x4 val;
                f16x4 hx;
#pragma unroll
                for (int r = 0; r < 4; ++r) {
                    val[r] = sum[r] * scl;
                    hx[r] = (f16)val[r];
                }
                if (xh_w) *(f16x4*)(xh_w + o) = hx;
                if (xs0) {                      // final head: sum fp16 partials
                    const f16x4 a0 = *(const f16x4*)(xs0 + o);
                    const f16x4 a1 = *(const f16x4*)(xs1 + o);
                    const f16x4 a2 = *(const f16x4*)(xs2 + o);
#pragma unroll
                    for (int r = 0; r < 4; ++r)
                        val[r] += (float)a0[r] + (float)a1[r] + (float)a2[r];
                }
                if (wout) {
                    f32x4 v2 = val;
                    if (accum) { const f32x4 old = *(const f32x4*)(out + o); v2 = v2 + old; }
                    *(f32x4*)(out + o) = v2;
                }
            }
        }
    }
}

// ---------------------------------------------------------------------------
// Workspace (big mode, ~100.3 MB):
//   xA @0 (16M: conv output, then reused as xh0), vT @16M (16M),
//   sh @32M (32M), Wh @64M (2M), ss @66M (256K), flags @66M+256K,
//   xB @68M (16M: xh1), xC @84M (16M: xh2)
// Fallback (< 101 MB ws): xB=xC=xA, fp32 out RMW.
// ---------------------------------------------------------------------------
extern "C" void kernel_launch(void* const* d_in, const int* in_sizes, int n_in,
                              void* d_out, int out_size, void* d_ws, size_t ws_size,
                              hipStream_t stream) {
    const float* x0    = (const float*)d_in[0];
    const int*   etype = (const int*)d_in[2];
    const float* W     = (const float*)d_in[3];
    const float* bias  = (const float*)d_in[4];
    float* out = (float*)d_out;

    char* ws = (char*)d_ws;
    f16*   xA    = (f16*)(ws);
    f16*   vT    = (f16*)(ws + (16u << 20));
    f16*   sh    = (f16*)(ws + (32u << 20));
    f16*   Wh    = (f16*)(ws + (64u << 20));
    float* ssb   = (float*)(ws + (66u << 20));
    int*   flags = (int*)(ws + (66u << 20) + 262144);

    const bool big = ws_size >= ((size_t)101 << 20);
    f16* xB = big ? (f16*)(ws + (68u << 20)) : xA;
    f16* xC = big ? (f16*)(ws + (84u << 20)) : xA;

    // fused prologue: x conv + W conv + flags + ss zeroing in ONE launch
    k_pre<<<9281, 256, 0, stream>>>(x0, xA, W, Wh, etype, flags, ssb);

    // per-head k_vs input and k_out fp16 destination
    f16* xin[H_]  = {xA, xA, xB, xC};
    f16* xdst[H_] = {xA, xB, xC, nullptr};

    for (int h = 0; h < H_; ++h) {
        float* ss = ssb + (size_t)h * B_ * S_;
        k_vs <<<1536, 256, 0, stream>>>(xin[h], Wh + (size_t)h * D_ * D_,
                                        bias + (size_t)h * D_, vT,
                                        etype, flags, sh, ss);
        if (big) {
            const bool last = (h == H_ - 1);
            k_out<<<512, 512, 0, stream>>>(vT, sh, ss, flags, xdst[h],
                                           last ? xA : nullptr,
                                           last ? xB : nullptr,
                                           last ? xC : nullptr,
                                           out, 0, last ? 1 : 0);
        } else {
            k_out<<<512, 512, 0, stream>>>(vT, sh, ss, flags,
                                           (h < H_ - 1) ? xA : nullptr,
                                           nullptr, nullptr, nullptr,
                                           out, h > 0, 1);
        }
    }
}

// Round 13
// 336.946 us; speedup vs baseline: 1.2400x; 1.0064x over previous
//
#include <hip/hip_runtime.h>
#include <math.h>

#define B_ 16
#define S_ 1024
#define D_ 512
#define H_ 4
#define INV_TEMP 0.044194173824159216f   // 1/sqrt(512)
#define C_SCALE 0.00390625f              // 2^-8: keeps head-4 scores inside fp16 range
#define OUT_SCALE 256.0f

typedef _Float16 f16;
typedef _Float16 f16x8 __attribute__((ext_vector_type(8)));
typedef _Float16 f16x4 __attribute__((ext_vector_type(4)));
typedef float f32x4 __attribute__((ext_vector_type(4)));

#define AS1(p) ((const __attribute__((address_space(1))) void*)(p))
#define AS3(p) ((__attribute__((address_space(3))) void*)(p))
#define MFMA __builtin_amdgcn_mfma_f32_16x16x32_f16

// ===========================================================================
// Fused prologue (single launch, 9281 blocks x 256 thr):
//   [0,8192)    : x fp32 -> fp16            (8M float4)
//   [8192,9216) : W fp32 -> fp16            (256K float4)
//   9216        : pad flags (128 lanes)
//   [9217,9281) : zero the 4 per-head Sum(s^2) accumulators (16K float4)
// ===========================================================================
__global__ __launch_bounds__(256)
void k_pre(const float* __restrict__ x0, f16* __restrict__ xh,
           const float* __restrict__ W, f16* __restrict__ Wh,
           const int* __restrict__ etype, int* __restrict__ flag,
           float* __restrict__ ssb)
{
    const int t = threadIdx.x;
    const int bi = blockIdx.x;
    if (bi < 8192) {
        const int i = bi * 256 + t;
        const float4 v = ((const float4*)x0)[i];
        f16x4 h; h[0] = (f16)v.x; h[1] = (f16)v.y; h[2] = (f16)v.z; h[3] = (f16)v.w;
        ((f16x4*)xh)[i] = h;
    } else if (bi < 9216) {
        const int i = (bi - 8192) * 256 + t;
        const float4 v = ((const float4*)W)[i];
        f16x4 h; h[0] = (f16)v.x; h[1] = (f16)v.y; h[2] = (f16)v.z; h[3] = (f16)v.w;
        ((f16x4*)Wh)[i] = h;
    } else if (bi == 9216) {
        if (t < 128) {
            const int b = t >> 3, kt = t & 7;
            const int* p = etype + b * S_ + kt * 128;
            int any0 = 0;
#pragma unroll
            for (int i = 0; i < 128; i += 4) {
                const int4 v = *(const int4*)(p + i);
                any0 |= (v.x == 0) | (v.y == 0) | (v.z == 0) | (v.w == 0);
            }
            flag[t] = any0;
        }
    } else {
        const int i = (bi - 9217) * 256 + t;     // 64 blocks cover 16K float4
        ((float4*)ssb)[i] = make_float4(0.f, 0.f, 0.f, 0.f);
    }
}

// ---------------------------------------------------------------------------
// Staging primitives. XOR swizzle throughout (proven zero-conflict, r10):
// 16B slot s of LDS row r holds global col-group (s ^ (r&7)); pre-swizzled
// GLOBAL source + matching XOR on ds_read (both-sides rule #21).
// ---------------------------------------------------------------------------
// 256-thread: 128 rows x 64 f16 (16 KB), 4 ops/thread (k_out groups)
__device__ __forceinline__ void stage128x64(const f16* __restrict__ src, int ld,
                                            char* lds0, int t)
{
    const int r = t >> 3;                         // [0,32)
    const int c = ((t & 7) ^ (r & 7)) << 3;
    const f16* g = src + (size_t)r * ld + c;
#pragma unroll
    for (int j = 0; j < 4; ++j)                   // (r+32j)&7 == r&7
        __builtin_amdgcn_global_load_lds(AS1(g + (size_t)(32 * j) * ld),
                                         AS3(lds0 + j * 4096 + t * 16), 16, 0, 0);
}

// 512-thread: 128 rows x 64 f16 (16 KB), 2 ops/thread
__device__ __forceinline__ void stageA128_512(const f16* __restrict__ src, int ld,
                                              char* lds0, int t)
{
    const int r = t >> 3;                         // [0,64)
    const int c = ((t & 7) ^ (r & 7)) << 3;
    const f16* g = src + (size_t)r * ld + c;
    __builtin_amdgcn_global_load_lds(AS1(g), AS3(lds0 + t * 16), 16, 0, 0);
    __builtin_amdgcn_global_load_lds(AS1(g + (size_t)64 * ld),
                                     AS3(lds0 + 8192 + t * 16), 16, 0, 0);
}

// 512-thread: 256 rows x 64 f16 (32 KB), 4 ops/thread
__device__ __forceinline__ void stageB256_512(const f16* __restrict__ src, int ld,
                                              char* lds0, int t)
{
    const int r = t >> 3;                         // [0,64)
    const int c = ((t & 7) ^ (r & 7)) << 3;
    const f16* g = src + (size_t)r * ld + c;
#pragma unroll
    for (int j = 0; j < 4; ++j)                   // (r+64j)&7 == r&7
        __builtin_amdgcn_global_load_lds(AS1(g + (size_t)(64 * j) * ld),
                                         AS3(lds0 + j * 8192 + t * 16), 16, 0, 0);
}

// One K=64 period for one wave: A rows wm*64+[0,64), B rows wn*64+[0,64).
// Works for both narrow (wn<2, 16KB B) and wide (wn<4, 32KB B) tiles.
__device__ __forceinline__ void mma64(const char* ldsA, const char* ldsB,
                                      int wm, int wn, int lr, int quad,
                                      f32x4 (*acc)[4])
{
#pragma unroll
    for (int kk = 0; kk < 2; ++kk) {
        f16x8 af[4], bf[4];
#pragma unroll
        for (int i = 0; i < 4; ++i) {
            const int row = wm * 64 + i * 16 + lr;
            af[i] = *(const f16x8*)(ldsA + (row << 7) +
                                    ((((kk << 2) + quad) ^ (row & 7)) << 4));
        }
#pragma unroll
        for (int j = 0; j < 4; ++j) {
            const int row = wn * 64 + j * 16 + lr;
            bf[j] = *(const f16x8*)(ldsB + (row << 7) +
                                    ((((kk << 2) + quad) ^ (row & 7)) << 4));
        }
#pragma unroll
        for (int i = 0; i < 4; ++i)
#pragma unroll
            for (int j = 0; j < 4; ++j)
                acc[i][j] = MFMA(af[i], bf[j], acc[i][j], 0, 0, 0);
    }
}

// ===========================================================================
// k_vs: WIDE 128x256 tiles, 512 thr / 8 waves (wm=w>>2 in {0,1}, wn=w&3).
// Per barrier period: stage A 16KB + B 32KB -> 256 MFMA (5.33 MFMA/KB vs 4
// for the 128x128 tile) and half the periods per output element. Same
// proven 2-barrier sync structure (rounds 3-7: don't touch), same ascending
// K order -> bitwise-identical results.
//   blocks [0,512):   scores; tile=(kt,qt2), bk=kt*128 (keys,M),
//                     bq=qt2*256 (queries,N). Early-exit kt<2*qt2 && !flag.
//   blocks [512,768): vT = ELU(x @ W^T + b)^T; bm=(idx&127)*128 rows,
//                     bn=(idx>>7)*256 features.
// sh NOT pre-zeroed: k_out's klist reads exactly the tiles written here.
// ===========================================================================
__global__ __launch_bounds__(512)
void k_vs(const f16* __restrict__ xh, const f16* __restrict__ Wh,
          const float* __restrict__ bias, f16* __restrict__ vT,
          const int* __restrict__ etype, const int* __restrict__ flag,
          f16* __restrict__ sh, float* __restrict__ ss)
{
    __shared__ __align__(16) char lds[49152];     // A @0 (16K), B @16384 (32K)
    const int t = threadIdx.x;
    const int lane = t & 63, lr = lane & 15, quad = lane >> 4;
    const int w = t >> 6, wm = w >> 2, wn = w & 3;

    if (blockIdx.x < 512) {
        // ---------------- scores ----------------
        const int i0 = blockIdx.x;
        const int xcd = i0 & 7, j0 = i0 >> 3;      // j0 in [0,64)
        const int b = 2 * xcd + (j0 & 1);
        const int tile = j0 >> 1;                  // [0,32)
        const int kt = tile & 7, qt2 = tile >> 3;  // kt in [0,8), qt2 in [0,4)
        // fully masked iff max_k (=128kt+127) <= min_q (=256qt2) and no pad
        if (kt < 2 * qt2 && !flag[b * 8 + kt]) return;
        const int bk = kt * 128, bq = qt2 * 256;

        const f16* xb = xh + (size_t)b * S_ * D_;
        const f16* A  = xb + (size_t)bk * D_;
        const f16* Bm = xb + (size_t)bq * D_;
        f32x4 acc[4][4] = {};
        for (int k0 = 0; k0 < D_; k0 += 64) {
            stageA128_512(A + k0, D_, lds, t);
            stageB256_512(Bm + k0, D_, lds + 16384, t);
            __syncthreads();
            mma64(lds, lds + 16384, wm, wn, lr, quad, acc);
            __syncthreads();
        }
        const float sc = INV_TEMP * C_SCALE;
        float ssq[4] = {0.0f, 0.0f, 0.0f, 0.0f};
#pragma unroll
        for (int i = 0; i < 4; ++i) {
            const int k4 = bk + wm * 64 + i * 16 + quad * 4;      // < 1024
            const int4 et = *(const int4*)(etype + b * S_ + k4);
            const int ev[4] = {et.x, et.y, et.z, et.w};
#pragma unroll
            for (int j = 0; j < 4; ++j) {
                const int q = bq + wn * 64 + j * 16 + lr;         // < 1024
                f16x4 hv;
#pragma unroll
                for (int r = 0; r < 4; ++r) {
                    const bool keep = ((k4 + r) > q) || (ev[r] == 0);
                    hv[r] = (f16)(keep ? acc[i][j][r] * sc : 0.0f);
                    const float fv = (float)hv[r];
                    ssq[j] += fv * fv;           // sum of squares of STORED fp16
                }
                *(f16x4*)(sh + ((size_t)b * S_ + q) * S_ + k4) = hv;
            }
        }
#pragma unroll
        for (int j = 0; j < 4; ++j) {
            float v = ssq[j];
            v += __shfl_xor(v, 16, 64);
            v += __shfl_xor(v, 32, 64);
            if (quad == 0) {
                const int q = bq + wn * 64 + j * 16 + lr;
                atomicAdd(ss + b * S_ + q, v);
            }
        }
    } else {
        // ---------------- vT = ELU(x @ W^T + b)^T ----------------
        const int idx = blockIdx.x - 512;          // [0,256)
        const int bm = (idx & 127) * 128;          // rows of x (one batch)
        const int bn = (idx >> 7) * 256;           // output features e
        const int b = bm >> 10;                    // batch (128 | 1024)
        f32x4 acc[4][4] = {};
        for (int k0 = 0; k0 < D_; k0 += 64) {
            stageA128_512(xh + (size_t)bm * D_ + k0, D_, lds, t);
            stageB256_512(Wh + (size_t)bn * D_ + k0, D_, lds + 16384, t);
            __syncthreads();
            mma64(lds, lds + 16384, wm, wn, lr, quad, acc);
            __syncthreads();
        }
#pragma unroll
        for (int j = 0; j < 4; ++j) {
            const int e = bn + wn * 64 + j * 16 + lr;             // < 512
            const float be = bias[e];
#pragma unroll
            for (int i = 0; i < 4; ++i) {
                const int s = (bm & 1023) + wm * 64 + i * 16 + quad * 4;
                f16x4 hv;
#pragma unroll
                for (int r = 0; r < 4; ++r) {
                    float z = acc[i][j][r] + be;
                    z = (z > 0.0f) ? z : (expf(z) - 1.0f);
                    hv[r] = (f16)z;
                }
                *(f16x4*)(vT + ((size_t)b * D_ + e) * S_ + s) = hv;
            }
        }
    }
}

// ===========================================================================
// k_out: EXACT round-10 proven version. 512 blocks x 512 thr (8 waves),
// two 4-wave K-half groups, BK=64 core, 128x128 tiles. Deterministic
// combine: g1 -> LDS -> g0 adds. Epilogue variants (host-selected):
//   big mode, h<3 : write per-head fp16 x-buffer only (no out traffic)
//   big mode, h==3: out = xh0 + xh1 + xh2 + xnew (single fp32 write)
//   fallback      : fp32 out RMW + xh write
// ===========================================================================
__global__ __launch_bounds__(512)
void k_out(const f16* __restrict__ vT, const f16* __restrict__ sh,
           const float* __restrict__ ss, const int* __restrict__ flag,
           f16* __restrict__ xh_w,
           const f16* __restrict__ xs0, const f16* __restrict__ xs1,
           const f16* __restrict__ xs2,
           float* __restrict__ out, const int accum, const int wout)
{
    __shared__ __align__(16) char lds[65536];   // g0 @0 (A,B 16K each), g1 @32768
    __shared__ int klist[32];
    __shared__ int kcnt;
    const int t = threadIdx.x;
    const int g = t >> 8;                       // K-half group
    const int tl = t & 255;                     // thread id within group
    const int w = tl >> 6, lane = tl & 63, lr = lane & 15, quad = lane >> 4;
    const int wm = w & 1, wn = w >> 1;
    const int i0 = blockIdx.x;
    const int xcd = i0 & 7, j0 = i0 >> 3;       // j0 in [0,64)
    const int b = 2 * xcd + (j0 & 1);
    const int tile = j0 >> 1;                   // [0,32)
    const int be = (tile & 3) * 128;            // e (M), fastest
    const int bq = (tile >> 2) * 128;           // q (N)
    const int qt = bq >> 7;

    if (t == 0) {
        int n = 0;
        for (int kc = 0; kc < 8; ++kc)
            if (kc >= qt || flag[b * 8 + kc]) { // kept chunk
                const int kb = kc * 128;
                klist[n] = kb; klist[n + 1] = kb + 32;
                klist[n + 2] = kb + 64; klist[n + 3] = kb + 96;
                n += 4;
            }
        kcnt = n;                               // multiple of 4, >= 4
    }
    __syncthreads();
    const int half = kcnt >> 1;                 // even (kcnt mult of 4)
    const int s0 = g ? half : 0;

    const f16* Abase = vT + ((size_t)b * D_ + be) * S_;
    const f16* Bbase = sh + ((size_t)b * S_ + bq) * S_;
    char* myl = lds + (g << 15);
    f32x4 acc[4][4] = {};
#pragma unroll 1
    for (int i = 0; i < half; i += 2) {         // 64 contiguous cols per step
        const int k0 = klist[s0 + i];
        stage128x64(Abase + k0, S_, myl, tl);
        stage128x64(Bbase + k0, S_, myl + 16384, tl);
        __syncthreads();
        mma64(myl, myl + 16384, wm, wn, lr, quad, acc);
        __syncthreads();
    }

    // deterministic half-K combine: g1 writes its partials, g0 adds.
    if (g == 1) {
#pragma unroll
        for (int j = 0; j < 4; ++j)
#pragma unroll
            for (int i = 0; i < 4; ++i)
                *(f32x4*)(lds + (((w * 16 + j * 4 + i) * 64 + lane) << 4)) = acc[i][j];
    }
    __syncthreads();
    if (g == 0) {
#pragma unroll
        for (int j = 0; j < 4; ++j) {
            const int q = bq + wn * 64 + j * 16 + lr;
            const float ssv = ss[b * S_ + q];
            const float scl = 1.0f / (C_SCALE * fmaxf(sqrtf(ssv) * OUT_SCALE, 1e-5f));
#pragma unroll
            for (int i = 0; i < 4; ++i) {
                const f32x4 other =
                    *(const f32x4*)(lds + (((w * 16 + j * 4 + i) * 64 + lane) << 4));
                const f32x4 sum = acc[i][j] + other;
                const int e4 = be + wm * 64 + i * 16 + quad * 4;
                const size_t o = ((size_t)b * S_ + q) * D_ + e4;
                f32x4 val;
                f16x4 hx;
#pragma unroll
                for (int r = 0; r < 4; ++r) {
                    val[r] = sum[r] * scl;
                    hx[r] = (f16)val[r];
                }
                if (xh_w) *(f16x4*)(xh_w + o) = hx;
                if (xs0) {                      // final head: sum fp16 partials
                    const f16x4 a0 = *(const f16x4*)(xs0 + o);
                    const f16x4 a1 = *(const f16x4*)(xs1 + o);
                    const f16x4 a2 = *(const f16x4*)(xs2 + o);
#pragma unroll
                    for (int r = 0; r < 4; ++r)
                        val[r] += (float)a0[r] + (float)a1[r] + (float)a2[r];
                }
                if (wout) {
                    f32x4 v2 = val;
                    if (accum) { const f32x4 old = *(const f32x4*)(out + o); v2 = v2 + old; }
                    *(f32x4*)(out + o) = v2;
                }
            }
        }
    }
}

// ---------------------------------------------------------------------------
// Workspace (big mode, ~100.3 MB):
//   xA @0 (16M: conv output, then reused as xh0), vT @16M (16M),
//   sh @32M (32M), Wh @64M (2M), ss @66M (256K), flags @66M+256K,
//   xB @68M (16M: xh1), xC @84M (16M: xh2)
// Fallback (< 101 MB ws): xB=xC=xA, fp32 out RMW.
// ---------------------------------------------------------------------------
extern "C" void kernel_launch(void* const* d_in, const int* in_sizes, int n_in,
                              void* d_out, int out_size, void* d_ws, size_t ws_size,
                              hipStream_t stream) {
    const float* x0    = (const float*)d_in[0];
    const int*   etype = (const int*)d_in[2];
    const float* W     = (const float*)d_in[3];
    const float* bias  = (const float*)d_in[4];
    float* out = (float*)d_out;

    char* ws = (char*)d_ws;
    f16*   xA    = (f16*)(ws);
    f16*   vT    = (f16*)(ws + (16u << 20));
    f16*   sh    = (f16*)(ws + (32u << 20));
    f16*   Wh    = (f16*)(ws + (64u << 20));
    float* ssb   = (float*)(ws + (66u << 20));
    int*   flags = (int*)(ws + (66u << 20) + 262144);

    const bool big = ws_size >= ((size_t)101 << 20);
    f16* xB = big ? (f16*)(ws + (68u << 20)) : xA;
    f16* xC = big ? (f16*)(ws + (84u << 20)) : xA;

    // fused prologue: x conv + W conv + flags + ss zeroing in ONE launch
    k_pre<<<9281, 256, 0, stream>>>(x0, xA, W, Wh, etype, flags, ssb);

    // per-head k_vs input and k_out fp16 destination
    f16* xin[H_]  = {xA, xA, xB, xC};
    f16* xdst[H_] = {xA, xB, xC, nullptr};

    for (int h = 0; h < H_; ++h) {
        float* ss = ssb + (size_t)h * B_ * S_;
        k_vs <<<768, 512, 0, stream>>>(xin[h], Wh + (size_t)h * D_ * D_,
                                       bias + (size_t)h * D_, vT,
                                       etype, flags, sh, ss);
        if (big) {
            const bool last = (h == H_ - 1);
            k_out<<<512, 512, 0, stream>>>(vT, sh, ss, flags, xdst[h],
                                           last ? xA : nullptr,
                                           last ? xB : nullptr,
                                           last ? xC : nullptr,
                                           out, 0, last ? 1 : 0);
        } else {
            k_out<<<512, 512, 0, stream>>>(vT, sh, ss, flags,
                                           (h < H_ - 1) ? xA : nullptr,
                                           nullptr, nullptr, nullptr,
                                           out, h > 0, 1);
        }
    }
}

// Round 14
// 332.613 us; speedup vs baseline: 1.2561x; 1.0130x over previous
//
#include <hip/hip_runtime.h>
#include <math.h>

#define B_ 16
#define S_ 1024
#define D_ 512
#define H_ 4
#define INV_TEMP 0.044194173824159216f   // 1/sqrt(512)
#define C_SCALE 0.00390625f              // 2^-8: keeps head-4 scores inside fp16 range
#define OUT_SCALE 256.0f

typedef _Float16 f16;
typedef _Float16 f16x8 __attribute__((ext_vector_type(8)));
typedef _Float16 f16x4 __attribute__((ext_vector_type(4)));
typedef float f32x4 __attribute__((ext_vector_type(4)));

#define AS1(p) ((const __attribute__((address_space(1))) void*)(p))
#define AS3(p) ((__attribute__((address_space(3))) void*)(p))
#define MFMA __builtin_amdgcn_mfma_f32_16x16x32_f16

// ===========================================================================
// Fused prologue (single launch, 9281 blocks x 256 thr):
//   [0,8192)    : x fp32 -> fp16, XCD-PINNED: block bi=xcd+8j handles chunk
//                 of batch b=2*xcd+(j&1) -> xh[b] lands in the L2 of the XCD
//                 that k_vs/k_out(b) run on (all consumers use xcd=b>>1).
//   [8192,9216) : W fp32 -> fp16            (256K float4)
//   9216        : pad flags (128 lanes)
//   [9217,9281) : zero the 4 per-head Sum(s^2) accumulators (16K float4)
// ===========================================================================
__global__ __launch_bounds__(256)
void k_pre(const float* __restrict__ x0, f16* __restrict__ xh,
           const float* __restrict__ W, f16* __restrict__ Wh,
           const int* __restrict__ etype, int* __restrict__ flag,
           float* __restrict__ ssb)
{
    const int t = threadIdx.x;
    const int bi = blockIdx.x;
    if (bi < 8192) {
        const int xcd = bi & 7, j = bi >> 3;          // j in [0,1024)
        const int b = 2 * xcd + (j & 1);
        const int off = j >> 1;                       // [0,512) chunks/batch
        const int i = (b * 512 + off) * 256 + t;      // float4 index
        const float4 v = ((const float4*)x0)[i];
        f16x4 h; h[0] = (f16)v.x; h[1] = (f16)v.y; h[2] = (f16)v.z; h[3] = (f16)v.w;
        ((f16x4*)xh)[i] = h;
    } else if (bi < 9216) {
        const int i = (bi - 8192) * 256 + t;
        const float4 v = ((const float4*)W)[i];
        f16x4 h; h[0] = (f16)v.x; h[1] = (f16)v.y; h[2] = (f16)v.z; h[3] = (f16)v.w;
        ((f16x4*)Wh)[i] = h;
    } else if (bi == 9216) {
        if (t < 128) {
            const int b = t >> 3, kt = t & 7;
            const int* p = etype + b * S_ + kt * 128;
            int any0 = 0;
#pragma unroll
            for (int i = 0; i < 128; i += 4) {
                const int4 v = *(const int4*)(p + i);
                any0 |= (v.x == 0) | (v.y == 0) | (v.z == 0) | (v.w == 0);
            }
            flag[t] = any0;
        }
    } else {
        const int i = (bi - 9217) * 256 + t;     // 64 blocks cover 16K float4
        ((float4*)ssb)[i] = make_float4(0.f, 0.f, 0.f, 0.f);
    }
}

// ---------------------------------------------------------------------------
// Staging primitives. XOR swizzle throughout (proven zero-conflict, r10):
// 16B slot s of LDS row r holds global col-group (s ^ (r&7)); pre-swizzled
// GLOBAL source + matching XOR on ds_read (both-sides rule #21).
// ---------------------------------------------------------------------------
// 256-thread: 128 rows x 64 f16 (16 KB), 4 ops/thread (k_out groups)
__device__ __forceinline__ void stage128x64(const f16* __restrict__ src, int ld,
                                            char* lds0, int t)
{
    const int r = t >> 3;                         // [0,32)
    const int c = ((t & 7) ^ (r & 7)) << 3;
    const f16* g = src + (size_t)r * ld + c;
#pragma unroll
    for (int j = 0; j < 4; ++j)                   // (r+32j)&7 == r&7
        __builtin_amdgcn_global_load_lds(AS1(g + (size_t)(32 * j) * ld),
                                         AS3(lds0 + j * 4096 + t * 16), 16, 0, 0);
}

// 512-thread: 128 rows x 64 f16 (16 KB), 2 ops/thread
__device__ __forceinline__ void stageA128_512(const f16* __restrict__ src, int ld,
                                              char* lds0, int t)
{
    const int r = t >> 3;                         // [0,64)
    const int c = ((t & 7) ^ (r & 7)) << 3;
    const f16* g = src + (size_t)r * ld + c;
    __builtin_amdgcn_global_load_lds(AS1(g), AS3(lds0 + t * 16), 16, 0, 0);
    __builtin_amdgcn_global_load_lds(AS1(g + (size_t)64 * ld),
                                     AS3(lds0 + 8192 + t * 16), 16, 0, 0);
}

// 512-thread: 256 rows x 64 f16 (32 KB), 4 ops/thread
__device__ __forceinline__ void stageB256_512(const f16* __restrict__ src, int ld,
                                              char* lds0, int t)
{
    const int r = t >> 3;                         // [0,64)
    const int c = ((t & 7) ^ (r & 7)) << 3;
    const f16* g = src + (size_t)r * ld + c;
#pragma unroll
    for (int j = 0; j < 4; ++j)                   // (r+64j)&7 == r&7
        __builtin_amdgcn_global_load_lds(AS1(g + (size_t)(64 * j) * ld),
                                         AS3(lds0 + j * 8192 + t * 16), 16, 0, 0);
}

// One K=64 period for one wave: A rows wm*64+[0,64), B rows wn*64+[0,64).
__device__ __forceinline__ void mma64(const char* ldsA, const char* ldsB,
                                      int wm, int wn, int lr, int quad,
                                      f32x4 (*acc)[4])
{
#pragma unroll
    for (int kk = 0; kk < 2; ++kk) {
        f16x8 af[4], bf[4];
#pragma unroll
        for (int i = 0; i < 4; ++i) {
            const int row = wm * 64 + i * 16 + lr;
            af[i] = *(const f16x8*)(ldsA + (row << 7) +
                                    ((((kk << 2) + quad) ^ (row & 7)) << 4));
        }
#pragma unroll
        for (int j = 0; j < 4; ++j) {
            const int row = wn * 64 + j * 16 + lr;
            bf[j] = *(const f16x8*)(ldsB + (row << 7) +
                                    ((((kk << 2) + quad) ^ (row & 7)) << 4));
        }
#pragma unroll
        for (int i = 0; i < 4; ++i)
#pragma unroll
            for (int j = 0; j < 4; ++j)
                acc[i][j] = MFMA(af[i], bf[j], acc[i][j], 0, 0, 0);
    }
}

// ===========================================================================
// k_vs: WIDE 128x256 tiles, 512 thr / 8 waves (round-13 proven).
//   blocks [0,512):   scores; XCD-pinned by batch (xcd = b>>1).
//   blocks [512,768): vT = ELU(x @ W^T + b)^T — NOW XCD-PINNED TOO:
//     idx&7 = xcd -> b = 2*xcd + ((idx>>3)&1); rest = idx>>4 in [0,16):
//     sq = rest&7 (m-tile within batch), bnT = rest>>3 (e-half).
//     Previously vT[b] was written round-robin across XCDs while k_out(b)
//     reads it on xcd=b>>1 (per-XCD L2s aren't shared) -> HBM round trips.
// sh NOT pre-zeroed: k_out's klist reads exactly the tiles written here.
// ===========================================================================
__global__ __launch_bounds__(512)
void k_vs(const f16* __restrict__ xh, const f16* __restrict__ Wh,
          const float* __restrict__ bias, f16* __restrict__ vT,
          const int* __restrict__ etype, const int* __restrict__ flag,
          f16* __restrict__ sh, float* __restrict__ ss)
{
    __shared__ __align__(16) char lds[49152];     // A @0 (16K), B @16384 (32K)
    const int t = threadIdx.x;
    const int lane = t & 63, lr = lane & 15, quad = lane >> 4;
    const int w = t >> 6, wm = w >> 2, wn = w & 3;

    if (blockIdx.x < 512) {
        // ---------------- scores ----------------
        const int i0 = blockIdx.x;
        const int xcd = i0 & 7, j0 = i0 >> 3;      // j0 in [0,64)
        const int b = 2 * xcd + (j0 & 1);
        const int tile = j0 >> 1;                  // [0,32)
        const int kt = tile & 7, qt2 = tile >> 3;  // kt in [0,8), qt2 in [0,4)
        // fully masked iff max_k (=128kt+127) <= min_q (=256qt2) and no pad
        if (kt < 2 * qt2 && !flag[b * 8 + kt]) return;
        const int bk = kt * 128, bq = qt2 * 256;

        const f16* xb = xh + (size_t)b * S_ * D_;
        const f16* A  = xb + (size_t)bk * D_;
        const f16* Bm = xb + (size_t)bq * D_;
        f32x4 acc[4][4] = {};
        for (int k0 = 0; k0 < D_; k0 += 64) {
            stageA128_512(A + k0, D_, lds, t);
            stageB256_512(Bm + k0, D_, lds + 16384, t);
            __syncthreads();
            mma64(lds, lds + 16384, wm, wn, lr, quad, acc);
            __syncthreads();
        }
        const float sc = INV_TEMP * C_SCALE;
        float ssq[4] = {0.0f, 0.0f, 0.0f, 0.0f};
#pragma unroll
        for (int i = 0; i < 4; ++i) {
            const int k4 = bk + wm * 64 + i * 16 + quad * 4;      // < 1024
            const int4 et = *(const int4*)(etype + b * S_ + k4);
            const int ev[4] = {et.x, et.y, et.z, et.w};
#pragma unroll
            for (int j = 0; j < 4; ++j) {
                const int q = bq + wn * 64 + j * 16 + lr;         // < 1024
                f16x4 hv;
#pragma unroll
                for (int r = 0; r < 4; ++r) {
                    const bool keep = ((k4 + r) > q) || (ev[r] == 0);
                    hv[r] = (f16)(keep ? acc[i][j][r] * sc : 0.0f);
                    const float fv = (float)hv[r];
                    ssq[j] += fv * fv;           // sum of squares of STORED fp16
                }
                *(f16x4*)(sh + ((size_t)b * S_ + q) * S_ + k4) = hv;
            }
        }
#pragma unroll
        for (int j = 0; j < 4; ++j) {
            float v = ssq[j];
            v += __shfl_xor(v, 16, 64);
            v += __shfl_xor(v, 32, 64);
            if (quad == 0) {
                const int q = bq + wn * 64 + j * 16 + lr;
                atomicAdd(ss + b * S_ + q, v);
            }
        }
    } else {
        // ---------------- vT = ELU(x @ W^T + b)^T (XCD-pinned) ----------------
        const int idx = blockIdx.x - 512;          // [0,256)
        const int xcd = idx & 7;
        const int b = 2 * xcd + ((idx >> 3) & 1);  // batch on this XCD
        const int rest = idx >> 4;                 // [0,16)
        const int sq = rest & 7;                   // m-tile within batch
        const int bnT = rest >> 3;                 // e-half
        const int bm = b * 1024 + sq * 128;        // global x row
        const int bn = bnT * 256;                  // output features e
        f32x4 acc[4][4] = {};
        for (int k0 = 0; k0 < D_; k0 += 64) {
            stageA128_512(xh + (size_t)bm * D_ + k0, D_, lds, t);
            stageB256_512(Wh + (size_t)bn * D_ + k0, D_, lds + 16384, t);
            __syncthreads();
            mma64(lds, lds + 16384, wm, wn, lr, quad, acc);
            __syncthreads();
        }
#pragma unroll
        for (int j = 0; j < 4; ++j) {
            const int e = bn + wn * 64 + j * 16 + lr;             // < 512
            const float be = bias[e];
#pragma unroll
            for (int i = 0; i < 4; ++i) {
                const int s = sq * 128 + wm * 64 + i * 16 + quad * 4;  // < 1024
                f16x4 hv;
#pragma unroll
                for (int r = 0; r < 4; ++r) {
                    float z = acc[i][j][r] + be;
                    z = (z > 0.0f) ? z : (expf(z) - 1.0f);
                    hv[r] = (f16)z;
                }
                *(f16x4*)(vT + ((size_t)b * D_ + e) * S_ + s) = hv;
            }
        }
    }
}

// ===========================================================================
// k_out: EXACT round-10 proven version. 512 blocks x 512 thr (8 waves),
// two 4-wave K-half groups, BK=64 core, 128x128 tiles. Deterministic
// combine: g1 -> LDS -> g0 adds. Epilogue variants (host-selected):
//   big mode, h<3 : write per-head fp16 x-buffer only (no out traffic)
//   big mode, h==3: out = xh0 + xh1 + xh2 + xnew (single fp32 write)
//   fallback      : fp32 out RMW + xh write
// ===========================================================================
__global__ __launch_bounds__(512)
void k_out(const f16* __restrict__ vT, const f16* __restrict__ sh,
           const float* __restrict__ ss, const int* __restrict__ flag,
           f16* __restrict__ xh_w,
           const f16* __restrict__ xs0, const f16* __restrict__ xs1,
           const f16* __restrict__ xs2,
           float* __restrict__ out, const int accum, const int wout)
{
    __shared__ __align__(16) char lds[65536];   // g0 @0 (A,B 16K each), g1 @32768
    __shared__ int klist[32];
    __shared__ int kcnt;
    const int t = threadIdx.x;
    const int g = t >> 8;                       // K-half group
    const int tl = t & 255;                     // thread id within group
    const int w = tl >> 6, lane = tl & 63, lr = lane & 15, quad = lane >> 4;
    const int wm = w & 1, wn = w >> 1;
    const int i0 = blockIdx.x;
    const int xcd = i0 & 7, j0 = i0 >> 3;       // j0 in [0,64)
    const int b = 2 * xcd + (j0 & 1);
    const int tile = j0 >> 1;                   // [0,32)
    const int be = (tile & 3) * 128;            // e (M), fastest
    const int bq = (tile >> 2) * 128;           // q (N)
    const int qt = bq >> 7;

    if (t == 0) {
        int n = 0;
        for (int kc = 0; kc < 8; ++kc)
            if (kc >= qt || flag[b * 8 + kc]) { // kept chunk
                const int kb = kc * 128;
                klist[n] = kb; klist[n + 1] = kb + 32;
                klist[n + 2] = kb + 64; klist[n + 3] = kb + 96;
                n += 4;
            }
        kcnt = n;                               // multiple of 4, >= 4
    }
    __syncthreads();
    const int half = kcnt >> 1;                 // even (kcnt mult of 4)
    const int s0 = g ? half : 0;

    const f16* Abase = vT + ((size_t)b * D_ + be) * S_;
    const f16* Bbase = sh + ((size_t)b * S_ + bq) * S_;
    char* myl = lds + (g << 15);
    f32x4 acc[4][4] = {};
#pragma unroll 1
    for (int i = 0; i < half; i += 2) {         // 64 contiguous cols per step
        const int k0 = klist[s0 + i];
        stage128x64(Abase + k0, S_, myl, tl);
        stage128x64(Bbase + k0, S_, myl + 16384, tl);
        __syncthreads();
        mma64(myl, myl + 16384, wm, wn, lr, quad, acc);
        __syncthreads();
    }

    // deterministic half-K combine: g1 writes its partials, g0 adds.
    if (g == 1) {
#pragma unroll
        for (int j = 0; j < 4; ++j)
#pragma unroll
            for (int i = 0; i < 4; ++i)
                *(f32x4*)(lds + (((w * 16 + j * 4 + i) * 64 + lane) << 4)) = acc[i][j];
    }
    __syncthreads();
    if (g == 0) {
#pragma unroll
        for (int j = 0; j < 4; ++j) {
            const int q = bq + wn * 64 + j * 16 + lr;
            const float ssv = ss[b * S_ + q];
            const float scl = 1.0f / (C_SCALE * fmaxf(sqrtf(ssv) * OUT_SCALE, 1e-5f));
#pragma unroll
            for (int i = 0; i < 4; ++i) {
                const f32x4 other =
                    *(const f32x4*)(lds + (((w * 16 + j * 4 + i) * 64 + lane) << 4));
                const f32x4 sum = acc[i][j] + other;
                const int e4 = be + wm * 64 + i * 16 + quad * 4;
                const size_t o = ((size_t)b * S_ + q) * D_ + e4;
                f32x4 val;
                f16x4 hx;
#pragma unroll
                for (int r = 0; r < 4; ++r) {
                    val[r] = sum[r] * scl;
                    hx[r] = (f16)val[r];
                }
                if (xh_w) *(f16x4*)(xh_w + o) = hx;
                if (xs0) {                      // final head: sum fp16 partials
                    const f16x4 a0 = *(const f16x4*)(xs0 + o);
                    const f16x4 a1 = *(const f16x4*)(xs1 + o);
                    const f16x4 a2 = *(const f16x4*)(xs2 + o);
#pragma unroll
                    for (int r = 0; r < 4; ++r)
                        val[r] += (float)a0[r] + (float)a1[r] + (float)a2[r];
                }
                if (wout) {
                    f32x4 v2 = val;
                    if (accum) { const f32x4 old = *(const f32x4*)(out + o); v2 = v2 + old; }
                    *(f32x4*)(out + o) = v2;
                }
            }
        }
    }
}

// ---------------------------------------------------------------------------
// Workspace (big mode, ~100.3 MB):
//   xA @0 (16M: conv output, then reused as xh0), vT @16M (16M),
//   sh @32M (32M), Wh @64M (2M), ss @66M (256K), flags @66M+256K,
//   xB @68M (16M: xh1), xC @84M (16M: xh2)
// Fallback (< 101 MB ws): xB=xC=xA, fp32 out RMW.
// ---------------------------------------------------------------------------
extern "C" void kernel_launch(void* const* d_in, const int* in_sizes, int n_in,
                              void* d_out, int out_size, void* d_ws, size_t ws_size,
                              hipStream_t stream) {
    const float* x0    = (const float*)d_in[0];
    const int*   etype = (const int*)d_in[2];
    const float* W     = (const float*)d_in[3];
    const float* bias  = (const float*)d_in[4];
    float* out = (float*)d_out;

    char* ws = (char*)d_ws;
    f16*   xA    = (f16*)(ws);
    f16*   vT    = (f16*)(ws + (16u << 20));
    f16*   sh    = (f16*)(ws + (32u << 20));
    f16*   Wh    = (f16*)(ws + (64u << 20));
    float* ssb   = (float*)(ws + (66u << 20));
    int*   flags = (int*)(ws + (66u << 20) + 262144);

    const bool big = ws_size >= ((size_t)101 << 20);
    f16* xB = big ? (f16*)(ws + (68u << 20)) : xA;
    f16* xC = big ? (f16*)(ws + (84u << 20)) : xA;

    // fused prologue: x conv + W conv + flags + ss zeroing in ONE launch
    k_pre<<<9281, 256, 0, stream>>>(x0, xA, W, Wh, etype, flags, ssb);

    // per-head k_vs input and k_out fp16 destination
    f16* xin[H_]  = {xA, xA, xB, xC};
    f16* xdst[H_] = {xA, xB, xC, nullptr};

    for (int h = 0; h < H_; ++h) {
        float* ss = ssb + (size_t)h * B_ * S_;
        k_vs <<<768, 512, 0, stream>>>(xin[h], Wh + (size_t)h * D_ * D_,
                                       bias + (size_t)h * D_, vT,
                                       etype, flags, sh, ss);
        if (big) {
            const bool last = (h == H_ - 1);
            k_out<<<512, 512, 0, stream>>>(vT, sh, ss, flags, xdst[h],
                                           last ? xA : nullptr,
                                           last ? xB : nullptr,
                                           last ? xC : nullptr,
                                           out, 0, last ? 1 : 0);
        } else {
            k_out<<<512, 512, 0, stream>>>(vT, sh, ss, flags,
                                           (h < H_ - 1) ? xA : nullptr,
                                           nullptr, nullptr, nullptr,
                                           out, h > 0, 1);
        }
    }
}

// Round 15
// 323.416 us; speedup vs baseline: 1.2918x; 1.0284x over previous
//
#include <hip/hip_runtime.h>
#include <math.h>

#define B_ 16
#define S_ 1024
#define D_ 512
#define H_ 4
#define INV_TEMP 0.044194173824159216f   // 1/sqrt(512)
#define C_SCALE 0.00390625f              // 2^-8: keeps head-4 scores inside fp16 range
#define OUT_SCALE 256.0f

typedef _Float16 f16;
typedef _Float16 f16x8 __attribute__((ext_vector_type(8)));
typedef _Float16 f16x4 __attribute__((ext_vector_type(4)));
typedef float f32x4 __attribute__((ext_vector_type(4)));

#define AS1(p) ((const __attribute__((address_space(1))) void*)(p))
#define AS3(p) ((__attribute__((address_space(3))) void*)(p))
#define MFMA __builtin_amdgcn_mfma_f32_16x16x32_f16

// raw barrier + sched fences (phase boundaries pinned; NO implicit vmcnt drain)
#define SBAR()                                                                 \
    do {                                                                       \
        __builtin_amdgcn_sched_barrier(0);                                     \
        __builtin_amdgcn_s_barrier();                                          \
        __builtin_amdgcn_sched_barrier(0);                                     \
    } while (0)
#define VMF(N)                                                                 \
    do {                                                                       \
        __builtin_amdgcn_sched_barrier(0);                                     \
        asm volatile("s_waitcnt vmcnt(" #N ")" ::: "memory");                  \
        __builtin_amdgcn_sched_barrier(0);                                     \
    } while (0)

// opaque LDS read: compiler can't see the LDS dependence -> it cannot insert
// its own vmcnt(0) drain before it (the r7 failure mode). We order it
// manually with VMF/SBAR/lgkmcnt.
__device__ __forceinline__ f16x8 ds_rd16(unsigned addr)
{
    f16x8 r;
    asm volatile("ds_read_b128 %0, %1" : "=v"(r) : "v"(addr));
    return r;
}

// ===========================================================================
// Fused prologue (single launch, 9281 blocks x 256 thr) — round-14 proven.
// ===========================================================================
__global__ __launch_bounds__(256)
void k_pre(const float* __restrict__ x0, f16* __restrict__ xh,
           const float* __restrict__ W, f16* __restrict__ Wh,
           const int* __restrict__ etype, int* __restrict__ flag,
           float* __restrict__ ssb)
{
    const int t = threadIdx.x;
    const int bi = blockIdx.x;
    if (bi < 8192) {
        const int xcd = bi & 7, j = bi >> 3;          // j in [0,1024)
        const int b = 2 * xcd + (j & 1);
        const int off = j >> 1;                       // [0,512) chunks/batch
        const int i = (b * 512 + off) * 256 + t;      // float4 index
        const float4 v = ((const float4*)x0)[i];
        f16x4 h; h[0] = (f16)v.x; h[1] = (f16)v.y; h[2] = (f16)v.z; h[3] = (f16)v.w;
        ((f16x4*)xh)[i] = h;
    } else if (bi < 9216) {
        const int i = (bi - 8192) * 256 + t;
        const float4 v = ((const float4*)W)[i];
        f16x4 h; h[0] = (f16)v.x; h[1] = (f16)v.y; h[2] = (f16)v.z; h[3] = (f16)v.w;
        ((f16x4*)Wh)[i] = h;
    } else if (bi == 9216) {
        if (t < 128) {
            const int b = t >> 3, kt = t & 7;
            const int* p = etype + b * S_ + kt * 128;
            int any0 = 0;
#pragma unroll
            for (int i = 0; i < 128; i += 4) {
                const int4 v = *(const int4*)(p + i);
                any0 |= (v.x == 0) | (v.y == 0) | (v.z == 0) | (v.w == 0);
            }
            flag[t] = any0;
        }
    } else {
        const int i = (bi - 9217) * 256 + t;     // 64 blocks cover 16K float4
        ((float4*)ssb)[i] = make_float4(0.f, 0.f, 0.f, 0.f);
    }
}

// ---------------------------------------------------------------------------
// 256-thread stage: 128 rows x 64 f16 (16 KB), 4 gload_lds/thread, linear
// dest + pre-swizzled global source (16B slot s of row r <- col-group
// s ^ (r&7); proven zero-conflict r10).
// ---------------------------------------------------------------------------
__device__ __forceinline__ void stage128x64(const f16* __restrict__ src, int ld,
                                            char* lds0, int t)
{
    const int r = t >> 3;                         // [0,32)
    const int c = ((t & 7) ^ (r & 7)) << 3;
    const f16* g = src + (size_t)r * ld + c;
#pragma unroll
    for (int j = 0; j < 4; ++j)                   // (r+32j)&7 == r&7
        __builtin_amdgcn_global_load_lds(AS1(g + (size_t)(32 * j) * ld),
                                         AS3(lds0 + j * 4096 + t * 16), 16, 0, 0);
}

// asm-read MMA for one K=64 step. Same kk-outer accumulation order as r10's
// mma64 -> bitwise-identical results.
__device__ __forceinline__ void mma_asm(unsigned aB, unsigned bB,
                                        const unsigned (*offA)[2],
                                        const unsigned (*offB)[2],
                                        f32x4 (*acc)[4])
{
    f16x8 af[4][2], bf[4][2];
#pragma unroll
    for (int kk = 0; kk < 2; ++kk) {
#pragma unroll
        for (int i = 0; i < 4; ++i) af[i][kk] = ds_rd16(aB + offA[i][kk]);
#pragma unroll
        for (int j = 0; j < 4; ++j) bf[j][kk] = ds_rd16(bB + offB[j][kk]);
    }
    asm volatile("s_waitcnt lgkmcnt(0)" ::: "memory");
    __builtin_amdgcn_sched_barrier(0);            // rule #18: pin MFMA after wait
#pragma unroll
    for (int kk = 0; kk < 2; ++kk)
#pragma unroll
        for (int i = 0; i < 4; ++i)
#pragma unroll
            for (int j = 0; j < 4; ++j)
                acc[i][j] = MFMA(af[i][kk], bf[j][kk], acc[i][j], 0, 0, 0);
}

// ---------------------------------------------------------------------------
// Counted-vmcnt double-buffered GEMM, K=512, 128x128 tile, 256 thr / 4 waves.
// Per step: stage(next buf) -> VMF(8) -> SBAR -> mma_asm(cur) -> SBAR.
// Ledger (8 gload_lds per stage, per wave): outstanding peaks at 16;
// VMF(8) retires exactly the previously-staged buffer; following SBAR makes
// it cross-wave; VMF(0) only at the tail. Stage latency hides under MFMA.
// Buffers compile-time (2x unroll; r4 lesson). LDS 64KB -> 2 blocks/CU.
// K ascending 64-steps -> bitwise-identical to the 2-phase version.
// ---------------------------------------------------------------------------
__device__ __forceinline__ void gemm_cnt(const f16* __restrict__ A, int ldA,
                                         const f16* __restrict__ Bm, int ldB,
                                         char* lds, int t,
                                         const unsigned (*offA)[2],
                                         const unsigned (*offB)[2],
                                         f32x4 (*acc)[4])
{
    const unsigned base = (unsigned)(unsigned long long)AS3(lds);
    // X: A@+0 B@+16384 | Y: A@+32768 B@+49152
    stage128x64(A, ldA, lds, t);
    stage128x64(Bm, ldB, lds + 16384, t);
#pragma unroll 1
    for (int i = 0; i < 3; ++i) {
        const int k1 = i * 128 + 64, k2 = i * 128 + 128;
        stage128x64(A + k1, ldA, lds + 32768, t);
        stage128x64(Bm + k1, ldB, lds + 49152, t);
        VMF(8); SBAR();
        mma_asm(base, base + 16384, offA, offB, acc);        // k = 128i
        SBAR();
        stage128x64(A + k2, ldA, lds, t);
        stage128x64(Bm + k2, ldB, lds + 16384, t);
        VMF(8); SBAR();
        mma_asm(base + 32768, base + 49152, offA, offB, acc); // k = 128i+64
        SBAR();
    }
    // X holds k=384 (staged in last loop iter); remaining k=448.
    stage128x64(A + 448, ldA, lds + 32768, t);
    stage128x64(Bm + 448, ldB, lds + 49152, t);
    VMF(8); SBAR();
    mma_asm(base, base + 16384, offA, offB, acc);             // k = 384
    SBAR();
    VMF(0); SBAR();
    mma_asm(base + 32768, base + 49152, offA, offB, acc);     // k = 448
}

// ===========================================================================
// k_vs: counted-vmcnt pipeline, 128x128 tiles, 256 thr / 4 waves, 1536 blks:
//   blocks [0,1024): scores (r10 mapping, XCD-pinned, ~44% early-exit)
//   blocks [1024,1536): vT = ELU(x @ W^T + b)^T, XCD-pinned (r14 lesson)
// sh NOT pre-zeroed: k_out's klist reads exactly the tiles written here.
// ===========================================================================
__global__ __launch_bounds__(256)
void k_vs(const f16* __restrict__ xh, const f16* __restrict__ Wh,
          const float* __restrict__ bias, f16* __restrict__ vT,
          const int* __restrict__ etype, const int* __restrict__ flag,
          f16* __restrict__ sh, float* __restrict__ ss)
{
    __shared__ __align__(16) char lds[65536];
    const int t = threadIdx.x;
    const int w = t >> 6, lane = t & 63, lr = lane & 15, quad = lane >> 4;
    const int wm = w & 1, wn = w >> 1;

    // swizzled ds_read byte offsets (row*128 + ((g ^ row&7)<<4), g=kk*4+quad)
    unsigned offA[4][2], offB[4][2];
#pragma unroll
    for (int i = 0; i < 4; ++i) {
        const int ra = wm * 64 + i * 16 + lr;
        const int rb = wn * 64 + i * 16 + lr;
#pragma unroll
        for (int kk = 0; kk < 2; ++kk) {
            offA[i][kk] = (unsigned)((ra << 7) + ((((kk << 2) + quad) ^ (ra & 7)) << 4));
            offB[i][kk] = (unsigned)((rb << 7) + ((((kk << 2) + quad) ^ (rb & 7)) << 4));
        }
    }

    if (blockIdx.x < 1024) {
        // ---------------- scores ----------------
        const int i0 = blockIdx.x;
        const int xcd = i0 & 7, j0 = i0 >> 3;          // j0 in [0,128)
        const int b = 2 * xcd + (j0 & 1);
        const int tile = j0 >> 1;                      // [0,64)
        const int bk = (tile & 7) * 128;               // keys (M)
        const int bq = (tile >> 3) * 128;              // queries (N)
        // fully-masked tile: exact zero; never computed/written/read.
        if (bk < bq && !flag[b * 8 + (bk >> 7)]) return;

        const f16* xb = xh + (size_t)b * S_ * D_;
        f32x4 acc[4][4] = {};
        gemm_cnt(xb + (size_t)bk * D_, D_, xb + (size_t)bq * D_, D_,
                 lds, t, offA, offB, acc);
        const float sc = INV_TEMP * C_SCALE;
        float ssq[4] = {0.0f, 0.0f, 0.0f, 0.0f};
#pragma unroll
        for (int i = 0; i < 4; ++i) {
            const int k4 = bk + wm * 64 + i * 16 + quad * 4;
            const int4 et = *(const int4*)(etype + b * S_ + k4);
            const int ev[4] = {et.x, et.y, et.z, et.w};
#pragma unroll
            for (int j = 0; j < 4; ++j) {
                const int q = bq + wn * 64 + j * 16 + lr;
                f16x4 hv;
#pragma unroll
                for (int r = 0; r < 4; ++r) {
                    const bool keep = ((k4 + r) > q) || (ev[r] == 0);
                    hv[r] = (f16)(keep ? acc[i][j][r] * sc : 0.0f);
                    const float fv = (float)hv[r];
                    ssq[j] += fv * fv;               // sum of squares of STORED fp16
                }
                *(f16x4*)(sh + ((size_t)b * S_ + q) * S_ + k4) = hv;
            }
        }
#pragma unroll
        for (int j = 0; j < 4; ++j) {
            float v = ssq[j];
            v += __shfl_xor(v, 16, 64);
            v += __shfl_xor(v, 32, 64);
            if (quad == 0) {
                const int q = bq + wn * 64 + j * 16 + lr;
                atomicAdd(ss + b * S_ + q, v);
            }
        }
    } else {
        // -------- vT = ELU(x @ W^T + b)^T, XCD-pinned by batch --------
        const int idx = blockIdx.x - 1024;             // [0,512)
        const int xcd = idx & 7;
        const int b = 2 * xcd + ((idx >> 3) & 1);
        const int rest = idx >> 4;                     // [0,32)
        const int sq = rest & 7;                       // m-tile within batch
        const int bn = (rest >> 3) * 128;              // e-tile
        const int bm = b * 1024 + sq * 128;
        f32x4 acc[4][4] = {};
        gemm_cnt(xh + (size_t)bm * D_, D_, Wh + (size_t)bn * D_, D_,
                 lds, t, offA, offB, acc);
#pragma unroll
        for (int j = 0; j < 4; ++j) {
            const int e = bn + wn * 64 + j * 16 + lr;
            const float be = bias[e];
#pragma unroll
            for (int i = 0; i < 4; ++i) {
                const int s = sq * 128 + wm * 64 + i * 16 + quad * 4;
                f16x4 hv;
#pragma unroll
                for (int r = 0; r < 4; ++r) {
                    float z = acc[i][j][r] + be;
                    z = (z > 0.0f) ? z : (expf(z) - 1.0f);
                    hv[r] = (f16)z;
                }
                *(f16x4*)(vT + ((size_t)b * D_ + e) * S_ + s) = hv;
            }
        }
    }
}

// plain-deref MMA for k_out (unchanged r14 path)
__device__ __forceinline__ void mma64(const char* ldsA, const char* ldsB,
                                      int wm, int wn, int lr, int quad,
                                      f32x4 (*acc)[4])
{
#pragma unroll
    for (int kk = 0; kk < 2; ++kk) {
        f16x8 af[4], bf[4];
#pragma unroll
        for (int i = 0; i < 4; ++i) {
            const int row = wm * 64 + i * 16 + lr;
            af[i] = *(const f16x8*)(ldsA + (row << 7) +
                                    ((((kk << 2) + quad) ^ (row & 7)) << 4));
        }
#pragma unroll
        for (int j = 0; j < 4; ++j) {
            const int row = wn * 64 + j * 16 + lr;
            bf[j] = *(const f16x8*)(ldsB + (row << 7) +
                                    ((((kk << 2) + quad) ^ (row & 7)) << 4));
        }
#pragma unroll
        for (int i = 0; i < 4; ++i)
#pragma unroll
            for (int j = 0; j < 4; ++j)
                acc[i][j] = MFMA(af[i], bf[j], acc[i][j], 0, 0, 0);
    }
}

// ===========================================================================
// k_out: EXACT round-10/14 proven version. 512 blocks x 512 thr (8 waves),
// two 4-wave K-half groups, BK=64 core, 128x128 tiles. Deterministic
// combine: g1 -> LDS -> g0 adds.
// ===========================================================================
__global__ __launch_bounds__(512)
void k_out(const f16* __restrict__ vT, const f16* __restrict__ sh,
           const float* __restrict__ ss, const int* __restrict__ flag,
           f16* __restrict__ xh_w,
           const f16* __restrict__ xs0, const f16* __restrict__ xs1,
           const f16* __restrict__ xs2,
           float* __restrict__ out, const int accum, const int wout)
{
    __shared__ __align__(16) char lds[65536];   // g0 @0 (A,B 16K each), g1 @32768
    __shared__ int klist[32];
    __shared__ int kcnt;
    const int t = threadIdx.x;
    const int g = t >> 8;                       // K-half group
    const int tl = t & 255;                     // thread id within group
    const int w = tl >> 6, lane = tl & 63, lr = lane & 15, quad = lane >> 4;
    const int wm = w & 1, wn = w >> 1;
    const int i0 = blockIdx.x;
    const int xcd = i0 & 7, j0 = i0 >> 3;       // j0 in [0,64)
    const int b = 2 * xcd + (j0 & 1);
    const int tile = j0 >> 1;                   // [0,32)
    const int be = (tile & 3) * 128;            // e (M), fastest
    const int bq = (tile >> 2) * 128;           // q (N)
    const int qt = bq >> 7;

    if (t == 0) {
        int n = 0;
        for (int kc = 0; kc < 8; ++kc)
            if (kc >= qt || flag[b * 8 + kc]) { // kept chunk
                const int kb = kc * 128;
                klist[n] = kb; klist[n + 1] = kb + 32;
                klist[n + 2] = kb + 64; klist[n + 3] = kb + 96;
                n += 4;
            }
        kcnt = n;                               // multiple of 4, >= 4
    }
    __syncthreads();
    const int half = kcnt >> 1;                 // even (kcnt mult of 4)
    const int s0 = g ? half : 0;

    const f16* Abase = vT + ((size_t)b * D_ + be) * S_;
    const f16* Bbase = sh + ((size_t)b * S_ + bq) * S_;
    char* myl = lds + (g << 15);
    f32x4 acc[4][4] = {};
#pragma unroll 1
    for (int i = 0; i < half; i += 2) {         // 64 contiguous cols per step
        const int k0 = klist[s0 + i];
        stage128x64(Abase + k0, S_, myl, tl);
        stage128x64(Bbase + k0, S_, myl + 16384, tl);
        __syncthreads();
        mma64(myl, myl + 16384, wm, wn, lr, quad, acc);
        __syncthreads();
    }

    // deterministic half-K combine: g1 writes its partials, g0 adds.
    if (g == 1) {
#pragma unroll
        for (int j = 0; j < 4; ++j)
#pragma unroll
            for (int i = 0; i < 4; ++i)
                *(f32x4*)(lds + (((w * 16 + j * 4 + i) * 64 + lane) << 4)) = acc[i][j];
    }
    __syncthreads();
    if (g == 0) {
#pragma unroll
        for (int j = 0; j < 4; ++j) {
            const int q = bq + wn * 64 + j * 16 + lr;
            const float ssv = ss[b * S_ + q];
            const float scl = 1.0f / (C_SCALE * fmaxf(sqrtf(ssv) * OUT_SCALE, 1e-5f));
#pragma unroll
            for (int i = 0; i < 4; ++i) {
                const f32x4 other =
                    *(const f32x4*)(lds + (((w * 16 + j * 4 + i) * 64 + lane) << 4));
                const f32x4 sum = acc[i][j] + other;
                const int e4 = be + wm * 64 + i * 16 + quad * 4;
                const size_t o = ((size_t)b * S_ + q) * D_ + e4;
                f32x4 val;
                f16x4 hx;
#pragma unroll
                for (int r = 0; r < 4; ++r) {
                    val[r] = sum[r] * scl;
                    hx[r] = (f16)val[r];
                }
                if (xh_w) *(f16x4*)(xh_w + o) = hx;
                if (xs0) {                      // final head: sum fp16 partials
                    const f16x4 a0 = *(const f16x4*)(xs0 + o);
                    const f16x4 a1 = *(const f16x4*)(xs1 + o);
                    const f16x4 a2 = *(const f16x4*)(xs2 + o);
#pragma unroll
                    for (int r = 0; r < 4; ++r)
                        val[r] += (float)a0[r] + (float)a1[r] + (float)a2[r];
                }
                if (wout) {
                    f32x4 v2 = val;
                    if (accum) { const f32x4 old = *(const f32x4*)(out + o); v2 = v2 + old; }
                    *(f32x4*)(out + o) = v2;
                }
            }
        }
    }
}

// ---------------------------------------------------------------------------
// Workspace (big mode, ~100.3 MB):
//   xA @0 (16M: conv output, then reused as xh0), vT @16M (16M),
//   sh @32M (32M), Wh @64M (2M), ss @66M (256K), flags @66M+256K,
//   xB @68M (16M: xh1), xC @84M (16M: xh2)
// Fallback (< 101 MB ws): xB=xC=xA, fp32 out RMW.
// ---------------------------------------------------------------------------
extern "C" void kernel_launch(void* const* d_in, const int* in_sizes, int n_in,
                              void* d_out, int out_size, void* d_ws, size_t ws_size,
                              hipStream_t stream) {
    const float* x0    = (const float*)d_in[0];
    const int*   etype = (const int*)d_in[2];
    const float* W     = (const float*)d_in[3];
    const float* bias  = (const float*)d_in[4];
    float* out = (float*)d_out;

    char* ws = (char*)d_ws;
    f16*   xA    = (f16*)(ws);
    f16*   vT    = (f16*)(ws + (16u << 20));
    f16*   sh    = (f16*)(ws + (32u << 20));
    f16*   Wh    = (f16*)(ws + (64u << 20));
    float* ssb   = (float*)(ws + (66u << 20));
    int*   flags = (int*)(ws + (66u << 20) + 262144);

    const bool big = ws_size >= ((size_t)101 << 20);
    f16* xB = big ? (f16*)(ws + (68u << 20)) : xA;
    f16* xC = big ? (f16*)(ws + (84u << 20)) : xA;

    // fused prologue: x conv + W conv + flags + ss zeroing in ONE launch
    k_pre<<<9281, 256, 0, stream>>>(x0, xA, W, Wh, etype, flags, ssb);

    // per-head k_vs input and k_out fp16 destination
    f16* xin[H_]  = {xA, xA, xB, xC};
    f16* xdst[H_] = {xA, xB, xC, nullptr};

    for (int h = 0; h < H_; ++h) {
        float* ss = ssb + (size_t)h * B_ * S_;
        k_vs <<<1536, 256, 0, stream>>>(xin[h], Wh + (size_t)h * D_ * D_,
                                        bias + (size_t)h * D_, vT,
                                        etype, flags, sh, ss);
        if (big) {
            const bool last = (h == H_ - 1);
            k_out<<<512, 512, 0, stream>>>(vT, sh, ss, flags, xdst[h],
                                           last ? xA : nullptr,
                                           last ? xB : nullptr,
                                           last ? xC : nullptr,
                                           out, 0, last ? 1 : 0);
        } else {
            k_out<<<512, 512, 0, stream>>>(vT, sh, ss, flags,
                                           (h < H_ - 1) ? xA : nullptr,
                                           nullptr, nullptr, nullptr,
                                           out, h > 0, 1);
        }
    }
}